// Round 7
// baseline (698.124 us; speedup 1.0000x reference)
//
#include <hip/hip_runtime.h>
#include <hip/hip_bf16.h>

// MoE (img/txt mixture) transformer block for MI355X.
// Round 7: clean round geometry (1 block/CU, long blocks => no tails);
// GELU fused into gateup epilogue via interleaved gate/up weight layout +
// LDS exchange; wo split-K=2 + fused rmsnorm2; down img split-4 (256 blocks,
// 1 clean round) + txt split-4 as short round 2. gemm8 K-loop unchanged.

typedef __hip_bfloat16 bf16;
typedef __attribute__((ext_vector_type(8))) __bf16 bf16x8;
typedef __attribute__((ext_vector_type(4))) float f32x4;

#define DEV __device__ __forceinline__

static constexpr int TT = 1536;
static constexpr int NHQ = 16, NKVH = 8, HDM = 128;

DEV void async_load16(const void* g, void* l) {
  typedef const __attribute__((address_space(1))) void* gas_t;
  typedef __attribute__((address_space(3))) void* las_t;
  __builtin_amdgcn_global_load_lds((gas_t)g, (las_t)l, 16, 0, 0);
}

DEV f32x4 mfma16(bf16x8 a, bf16x8 b, f32x4 c) {
  return __builtin_amdgcn_mfma_f32_16x16x32_bf16(a, b, c, 0, 0, 0);
}

DEV float bf2f(bf16 x) { return __bfloat162float(x); }
DEV bf16  f2bf(float x) { return __float2bfloat16(x); }

// ---------------------------------------------------------------------------
// Weight transpose+convert: f32 [K][N] -> bf16 [phys(N)][K], with optional
// output-row remap phys = r_base + n + ((n>>r_lsh)*r_skip) (gate/up interleave)
// ---------------------------------------------------------------------------
struct TJob { const float* src; bf16* dst; int K; int N; int r_base, r_lsh, r_skip; };
struct TJobs { TJob j[14]; int cum[15]; };

__global__ __launch_bounds__(256) void wt_transpose(TJobs P) {
  __shared__ bf16 tile[64][65];
  int bid = blockIdx.x;
  int ji = 0;
  while (ji < 13 && bid >= P.cum[ji + 1]) ji++;
  const TJob jb = P.j[ji];
  int rel = bid - P.cum[ji];
  int ntc = jb.N >> 6;
  int tr = rel / ntc, tc = rel - tr * ntc;
  int r0 = tr << 6, c0 = tc << 6;
  int t = threadIdx.x;
  #pragma unroll
  for (int i = 0; i < 16; i++) {
    int idx = i * 256 + t;
    int r = idx >> 6, c = idx & 63;
    tile[c][r] = f2bf(jb.src[(size_t)(r0 + r) * jb.N + c0 + c]);
  }
  __syncthreads();
  #pragma unroll
  for (int i = 0; i < 16; i++) {
    int idx = i * 256 + t;
    int r = idx >> 6, c = idx & 63;
    int n = c0 + r;
    int phys = jb.r_base + n + ((n >> jb.r_lsh) * jb.r_skip);
    jb.dst[(size_t)phys * jb.K + r0 + c] = tile[r][c];
  }
}

// bf16 transpose for V: v_all [B*TT][NKVH*HDM] -> vt [B*NKVH][HDM][TT]
__global__ __launch_bounds__(256) void transpose_v(const bf16* __restrict__ v_all,
                                                   bf16* __restrict__ vt) {
  int st = blockIdx.x, ht = blockIdx.y, bk = blockIdx.z;
  int b = bk >> 3, kv = bk & 7;
  __shared__ bf16 tile[64][65];
  int t = threadIdx.x;
  int s0 = st * 64, h0 = ht * 64;
  #pragma unroll
  for (int i = 0; i < 16; i++) {
    int idx = i * 256 + t;
    int r = idx >> 6, c = idx & 63;
    tile[c][r] = v_all[((size_t)(b * TT + s0 + r) * NKVH + kv) * HDM + h0 + c];
  }
  __syncthreads();
  #pragma unroll
  for (int i = 0; i < 16; i++) {
    int idx = i * 256 + t;
    int r = idx >> 6, c = idx & 63;
    vt[((size_t)bk * HDM + h0 + r) * TT + s0 + c] = tile[r][c];
  }
}

// ---------------------------------------------------------------------------
// RMSNorm (single input)
// ---------------------------------------------------------------------------
template <int DV>
__global__ __launch_bounds__(256) void rmsnorm_k(const float* __restrict__ x,
                                                 const float* __restrict__ sc,
                                                 bf16* __restrict__ out) {
  const int D = DV * 1024;
  int row = blockIdx.x, t = threadIdx.x;
  const float4* xr = reinterpret_cast<const float4*>(x + (size_t)row * D);
  float4 v[DV];
  float ss = 0.f;
  #pragma unroll
  for (int i = 0; i < DV; i++) {
    v[i] = xr[t + i * 256];
    ss += v[i].x * v[i].x + v[i].y * v[i].y + v[i].z * v[i].z + v[i].w * v[i].w;
  }
  #pragma unroll
  for (int o = 1; o < 64; o <<= 1) ss += __shfl_xor(ss, o);
  __shared__ float red[4];
  if ((t & 63) == 0) red[t >> 6] = ss;
  __syncthreads();
  float r = rsqrtf((red[0] + red[1] + red[2] + red[3]) * (1.0f / D) + 1e-6f);
  bf16* orow = out + (size_t)row * D;
  #pragma unroll
  for (int i = 0; i < DV; i++) {
    int c = (t + i * 256) * 4;
    orow[c + 0] = f2bf(v[i].x * r * (1.f + sc[c + 0]));
    orow[c + 1] = f2bf(v[i].y * r * (1.f + sc[c + 1]));
    orow[c + 2] = f2bf(v[i].z * r * (1.f + sc[c + 2]));
    orow[c + 3] = f2bf(v[i].w * r * (1.f + sc[c + 3]));
  }
}

// ---------------------------------------------------------------------------
// RMSNorm over (p0+p1+x): fused wo split-K=2 reduce + pre-FFW norm
// ---------------------------------------------------------------------------
template <int DV>
__global__ __launch_bounds__(256) void rmsnorm2_k(
    const float* __restrict__ p0, const float* __restrict__ p1,
    const float* __restrict__ x, const float* __restrict__ sc,
    bf16* __restrict__ out) {
  const int D = DV * 1024;
  int row = blockIdx.x, t = threadIdx.x;
  size_t rb = (size_t)row * (D / 4);
  const float4* r0 = reinterpret_cast<const float4*>(p0) + rb;
  const float4* r1 = reinterpret_cast<const float4*>(p1) + rb;
  const float4* xr = reinterpret_cast<const float4*>(x) + rb;
  float4 v[DV];
  float ss = 0.f;
  #pragma unroll
  for (int i = 0; i < DV; i++) {
    int idx = t + i * 256;
    float4 a = r0[idx], b = r1[idx], e = xr[idx];
    v[i] = make_float4(a.x + b.x + e.x, a.y + b.y + e.y,
                       a.z + b.z + e.z, a.w + b.w + e.w);
    ss += v[i].x * v[i].x + v[i].y * v[i].y + v[i].z * v[i].z + v[i].w * v[i].w;
  }
  #pragma unroll
  for (int o = 1; o < 64; o <<= 1) ss += __shfl_xor(ss, o);
  __shared__ float red[4];
  if ((t & 63) == 0) red[t >> 6] = ss;
  __syncthreads();
  float r = rsqrtf((red[0] + red[1] + red[2] + red[3]) * (1.0f / D) + 1e-6f);
  bf16* orow = out + (size_t)row * D;
  #pragma unroll
  for (int i = 0; i < DV; i++) {
    int c = (t + i * 256) * 4;
    orow[c + 0] = f2bf(v[i].x * r * (1.f + sc[c + 0]));
    orow[c + 1] = f2bf(v[i].y * r * (1.f + sc[c + 1]));
    orow[c + 2] = f2bf(v[i].z * r * (1.f + sc[c + 2]));
    orow[c + 3] = f2bf(v[i].w * r * (1.f + sc[c + 3]));
  }
}

// ---------------------------------------------------------------------------
// RoPE in-place
// ---------------------------------------------------------------------------
__global__ __launch_bounds__(256) void rope_inplace(bf16* __restrict__ x, int lognh,
                                                    float scale) {
  int gid = blockIdx.x * 256 + threadIdx.x;
  int i = gid & 63;
  int rh = gid >> 6;
  int row = rh >> lognh;
  int pos = row >= TT ? row - TT : row;
  float fr = expf(-9.210340371976184f * ((float)(2 * i) * (1.0f / 128.0f)));
  float th = (float)pos * fr;
  float s, c;
  sincosf(th, &s, &c);
  bf16* p = x + (size_t)rh * HDM;
  float x1 = bf2f(p[i]), x2 = bf2f(p[i + 64]);
  p[i]      = f2bf((x1 * c - x2 * s) * scale);
  p[i + 64] = f2bf((x2 * c + x1 * s) * scale);
}

// ---------------------------------------------------------------------------
// 8-phase 256x256 GEMM (T2+T3+T4+T5) - proven K-loop.
// fuse=1: gate/up interleaved B (rows 0-127 gate, 128-255 up per 256-tile);
// epilogue exchanges up-acc through LDS and writes act = gelu(gate)*up
// (128 output cols per block, c_stride = act row stride).
// ---------------------------------------------------------------------------
struct G8Job {
  const bf16* A; const bf16* B; bf16* Cb; float* Cf;
  int K, N, lda, ldb;
  int a_base, a_lsh, a_lskip;
  int c_base, c_lsh, c_lskip, c_stride;
  int fuse;
};
struct G8Jobs { G8Job j[8]; int cum[9]; int nj; };

#define G8_BAR_MFMA(MH, NH)                                        \
  __builtin_amdgcn_s_barrier();                                    \
  asm volatile("s_waitcnt lgkmcnt(0)" ::: "memory");               \
  __builtin_amdgcn_sched_barrier(0);                               \
  __builtin_amdgcn_s_setprio(1);                                   \
  _Pragma("unroll")                                                \
  for (int i = 0; i < 4; i++)                                      \
    _Pragma("unroll")                                              \
    for (int nj2 = 0; nj2 < 2; nj2++)                              \
      _Pragma("unroll")                                            \
      for (int kk = 0; kk < 2; kk++)                               \
        acc[(MH)*4 + i][(NH)*2 + nj2] = mfma16(                    \
            afr[i][kk], bfr[(NH)*2 + nj2][kk],                     \
            acc[(MH)*4 + i][(NH)*2 + nj2]);                        \
  __builtin_amdgcn_s_setprio(0);                                   \
  __builtin_amdgcn_s_barrier();                                    \
  asm volatile("" ::: "memory");

__global__ __launch_bounds__(512, 2) void gemm8(G8Jobs P) {
  extern __shared__ __align__(16) bf16 lds8[];
  int bid = blockIdx.x;
  int ji = 0;
  while (ji < P.nj - 1 && bid >= P.cum[ji + 1]) ji++;
  const G8Job jb = P.j[ji];
  int rel = bid - P.cum[ji];
  int tn = jb.N >> 8;
  int bm = rel / tn, bn = rel - bm * tn;
  const int m0 = bm << 8, n0 = bn << 8;
  const int K = jb.K;
  const int nk = K >> 6;

  const int tid = threadIdx.x;
  const int w = tid >> 6, l = tid & 63;
  const int lr = l & 15, lk = l >> 4;
  const int wr = w >> 2, wc = w & 3;

  const int r0 = tid >> 3, sl0 = (tid & 7) ^ (r0 & 7);
  const int dst0 = (w * 64) * 8;
  const int dst1 = (512 + w * 64) * 8;

  auto stage = [&](int ht, int hq) {
    int k0 = ht << 6;
    bf16* ldsb = lds8 + ((ht & 1) * 32768 + hq * 8192);
    if (hq < 2) {
      int ma = m0 + hq * 128;
      int mr0 = ma + r0, mr1 = ma + 64 + r0;
      int pr0 = jb.a_base + mr0 + ((mr0 >> jb.a_lsh) * jb.a_lskip);
      int pr1 = jb.a_base + mr1 + ((mr1 >> jb.a_lsh) * jb.a_lskip);
      async_load16(jb.A + (size_t)pr0 * jb.lda + k0 + sl0 * 8, ldsb + dst0);
      async_load16(jb.A + (size_t)pr1 * jb.lda + k0 + sl0 * 8, ldsb + dst1);
    } else {
      int nb = n0 + (hq - 2) * 128;
      async_load16(jb.B + (size_t)(nb + r0) * jb.ldb + k0 + sl0 * 8, ldsb + dst0);
      async_load16(jb.B + (size_t)(nb + 64 + r0) * jb.ldb + k0 + sl0 * 8, ldsb + dst1);
    }
  };

  f32x4 acc[8][4];
  #pragma unroll
  for (int i = 0; i < 8; i++)
    #pragma unroll
    for (int j = 0; j < 4; j++) acc[i][j] = (f32x4){0.f, 0.f, 0.f, 0.f};

  const int s0 = ((0 * 4 + lk) ^ (lr & 7)) * 8;
  const int s1 = ((1 * 4 + lk) ^ (lr & 7)) * 8;
  const int browb = (wc & 1) * 64;

  #pragma unroll
  for (int hq = 0; hq < 4; hq++) stage(0, hq);
  #pragma unroll
  for (int hq = 0; hq < 4; hq++) stage(1, hq);
  asm volatile("s_waitcnt vmcnt(8)" ::: "memory");
  __builtin_amdgcn_s_barrier();
  asm volatile("" ::: "memory");

  bf16x8 afr[4][2], bfr[4][2];

  for (int t = 0; t < nk; t++) {
    const bf16* bufA = lds8 + (t & 1) * 32768 + wr * 8192;
    const bf16* bufB = lds8 + (t & 1) * 32768 + 16384 + (wc >> 1) * 8192;
    const bool st = (t + 2 < nk);

    #pragma unroll
    for (int i = 0; i < 4; i++) {
      int rb = (i * 16 + lr) * 64;
      afr[i][0] = *reinterpret_cast<const bf16x8*>(bufA + rb + s0);
      afr[i][1] = *reinterpret_cast<const bf16x8*>(bufA + rb + s1);
    }
    #pragma unroll
    for (int ni = 0; ni < 2; ni++) {
      int rb = (browb + ni * 16 + lr) * 64;
      bfr[ni][0] = *reinterpret_cast<const bf16x8*>(bufB + rb + s0);
      bfr[ni][1] = *reinterpret_cast<const bf16x8*>(bufB + rb + s1);
    }
    G8_BAR_MFMA(0, 0)

    #pragma unroll
    for (int ni = 2; ni < 4; ni++) {
      int rb = (browb + ni * 16 + lr) * 64;
      bfr[ni][0] = *reinterpret_cast<const bf16x8*>(bufB + rb + s0);
      bfr[ni][1] = *reinterpret_cast<const bf16x8*>(bufB + rb + s1);
    }
    G8_BAR_MFMA(0, 1)

    #pragma unroll
    for (int i = 0; i < 4; i++) {
      int rb = ((i + 4) * 16 + lr) * 64;
      afr[i][0] = *reinterpret_cast<const bf16x8*>(bufA + rb + s0);
      afr[i][1] = *reinterpret_cast<const bf16x8*>(bufA + rb + s1);
    }
    if (st) { stage(t + 2, 2); stage(t + 2, 3); }
    G8_BAR_MFMA(1, 0)

    if (st) {
      stage(t + 2, 0); stage(t + 2, 1);
      asm volatile("s_waitcnt vmcnt(8)" ::: "memory");
    } else if (t == nk - 2) {
      asm volatile("s_waitcnt vmcnt(0)" ::: "memory");
    }
    G8_BAR_MFMA(1, 1)
  }

  if (jb.fuse) {
    // gate rows = B rows 0..127 (wc<2), up rows = 128..255 (wc>=2).
    float* xch = reinterpret_cast<float*>(lds8);
    if (wc >= 2) {
      float* slot = xch + (wr * 2 + (wc - 2)) * 8192;
      #pragma unroll
      for (int mi = 0; mi < 8; mi++)
        #pragma unroll
        for (int jj = 0; jj < 4; jj++) {
          int row = mi * 16 + lk * 4 + jj;
          #pragma unroll
          for (int ni = 0; ni < 4; ni++)
            slot[row * 64 + ni * 16 + lr] = acc[mi][ni][jj];
        }
    }
    __syncthreads();
    if (wc < 2) {
      const float* slot = xch + (wr * 2 + wc) * 8192;
      int colbase = (n0 >> 1) + wc * 64;  // bn*128 + wc*64
      #pragma unroll
      for (int mi = 0; mi < 8; mi++)
        #pragma unroll
        for (int jj = 0; jj < 4; jj++) {
          int m = m0 + wr * 128 + mi * 16 + lk * 4 + jj;
          int row = mi * 16 + lk * 4 + jj;
          bf16* drow = jb.Cb + (size_t)m * jb.c_stride + colbase;
          #pragma unroll
          for (int ni = 0; ni < 4; ni++) {
            float g = acc[mi][ni][jj];
            float u = slot[row * 64 + ni * 16 + lr];
            float tt = tanhf(0.7978845608028654f * (g + 0.044715f * g * g * g));
            drow[ni * 16 + lr] = f2bf(0.5f * g * (1.f + tt) * u);
          }
        }
    }
  } else if (jb.Cf) {
    #pragma unroll
    for (int mi = 0; mi < 8; mi++)
      #pragma unroll
      for (int jj = 0; jj < 4; jj++) {
        int m = m0 + wr * 128 + mi * 16 + lk * 4 + jj;
        float* drow = jb.Cf + (size_t)m * jb.c_stride + n0 + wc * 64;
        #pragma unroll
        for (int ni = 0; ni < 4; ni++) drow[ni * 16 + lr] = acc[mi][ni][jj];
      }
  } else {
    #pragma unroll
    for (int mi = 0; mi < 8; mi++)
      #pragma unroll
      for (int jj = 0; jj < 4; jj++) {
        int m = m0 + wr * 128 + mi * 16 + lk * 4 + jj;
        int crow = jb.c_base + m + ((m >> jb.c_lsh) * jb.c_lskip);
        bf16* drow = jb.Cb + (size_t)crow * jb.c_stride + n0 + wc * 64;
        #pragma unroll
        for (int ni = 0; ni < 4; ni++) drow[ni * 16 + lr] = f2bf(acc[mi][ni][jj]);
      }
  }
}

// ---------------------------------------------------------------------------
// Down split-K reduce: out += p1+p2+p3+x for img and txt
// ---------------------------------------------------------------------------
__global__ __launch_bounds__(256) void reduce_down(
    float* __restrict__ oi, const float* __restrict__ a1,
    const float* __restrict__ a2, const float* __restrict__ a3,
    const float* __restrict__ xi, int n4i,
    float* __restrict__ ot, const float* __restrict__ b1,
    const float* __restrict__ b2, const float* __restrict__ b3,
    const float* __restrict__ xt, int n4t) {
  int tot = n4i + n4t;
  for (int idx = blockIdx.x * 256 + threadIdx.x; idx < tot; idx += gridDim.x * 256) {
    if (idx < n4i) {
      float4 d = ((const float4*)oi)[idx];
      float4 a = ((const float4*)a1)[idx];
      float4 b = ((const float4*)a2)[idx];
      float4 c = ((const float4*)a3)[idx];
      float4 e = ((const float4*)xi)[idx];
      ((float4*)oi)[idx] = make_float4(d.x + a.x + b.x + c.x + e.x,
                                       d.y + a.y + b.y + c.y + e.y,
                                       d.z + a.z + b.z + c.z + e.z,
                                       d.w + a.w + b.w + c.w + e.w);
    } else {
      int i = idx - n4i;
      float4 d = ((const float4*)ot)[i];
      float4 a = ((const float4*)b1)[i];
      float4 b = ((const float4*)b2)[i];
      float4 c = ((const float4*)b3)[i];
      float4 e = ((const float4*)xt)[i];
      ((float4*)ot)[i] = make_float4(d.x + a.x + b.x + c.x + e.x,
                                     d.y + a.y + b.y + c.y + e.y,
                                     d.z + a.z + b.z + c.z + e.z,
                                     d.w + a.w + b.w + c.w + e.w);
    }
  }
}

// ---------------------------------------------------------------------------
// Flash attention with softcap (no online max; logits bounded by +-50).
// ---------------------------------------------------------------------------
__global__ __launch_bounds__(256) void attn_k(const bf16* __restrict__ q_all,
                                              const bf16* __restrict__ k_all,
                                              const bf16* __restrict__ vt,
                                              bf16* __restrict__ attn_o) {
  const int qt = blockIdx.x;
  const int n = blockIdx.y;
  const int b = blockIdx.z;
  const int kv = n >> 1;
  const int tid = threadIdx.x, w = tid >> 6, l = tid & 63;
  const int lr = l & 15, lk = l >> 4;
  __shared__ __align__(16) bf16 Ksm[64 * 128];
  __shared__ __align__(16) bf16 Vsm[128 * 64];
  __shared__ __align__(16) bf16 Psm[4][16][72];

  bf16x8 qf[4];
  {
    int t = qt * 64 + w * 16 + lr;
    const bf16* qp = q_all + ((size_t)(b * TT + t) * NHQ + n) * HDM;
    #pragma unroll
    for (int kk = 0; kk < 4; kk++)
      qf[kk] = *reinterpret_cast<const bf16x8*>(qp + kk * 32 + lk * 8);
  }
  f32x4 acc_o[8];
  #pragma unroll
  for (int i = 0; i < 8; i++) acc_o[i] = (f32x4){0.f, 0.f, 0.f, 0.f};
  float den[4] = {0.f, 0.f, 0.f, 0.f};

  for (int st = 0; st < TT / 64; st++) {
    __syncthreads();
    #pragma unroll
    for (int i = 0; i < 4; i++) {
      int cb = (w * 4 + i) * 64;
      int c = cb + l;
      {
        int srow = c >> 4, c16 = c & 15;
        const bf16* g = k_all + ((size_t)(b * TT + st * 64 + srow) * NKVH + kv) * HDM +
                        ((c16 ^ (srow & 7)) << 3);
        async_load16(g, Ksm + cb * 8);
      }
      {
        int hrow = c >> 3, c8 = c & 7;
        const bf16* g = vt + ((size_t)(b * NKVH + kv) * HDM + hrow) * TT + st * 64 +
                        ((c8 ^ (hrow & 7)) << 3);
        async_load16(g, Vsm + cb * 8);
      }
    }
    __syncthreads();
    #pragma unroll
    for (int sf = 0; sf < 4; sf++) {
      f32x4 s4 = (f32x4){0.f, 0.f, 0.f, 0.f};
      int sl = sf * 16 + lr;
      #pragma unroll
      for (int kk = 0; kk < 4; kk++) {
        int e = kk * 32 + lk * 8;
        bf16x8 kf = *reinterpret_cast<const bf16x8*>(
            Ksm + sl * 128 + ((((e >> 3) ^ (sl & 7))) << 3));
        s4 = mfma16(qf[kk], kf, s4);
      }
      #pragma unroll
      for (int j = 0; j < 4; j++) {
        float xv = s4[j];
        float tcap = tanhf(xv * 0.02f) * 50.f;
        float p = __expf(tcap);
        Psm[w][lk * 4 + j][sf * 16 + lr] = f2bf(p);
        p += __shfl_xor(p, 1);
        p += __shfl_xor(p, 2);
        p += __shfl_xor(p, 4);
        p += __shfl_xor(p, 8);
        den[j] += p;
      }
    }
    #pragma unroll
    for (int kk2 = 0; kk2 < 2; kk2++) {
      bf16x8 pa = *reinterpret_cast<const bf16x8*>(&Psm[w][lr][kk2 * 32 + lk * 8]);
      #pragma unroll
      for (int hf = 0; hf < 8; hf++) {
        int h = hf * 16 + lr;
        int e2 = kk2 * 32 + lk * 8;
        bf16x8 vb = *reinterpret_cast<const bf16x8*>(
            Vsm + h * 64 + ((((e2 >> 3) ^ (h & 7))) << 3));
        acc_o[hf] = mfma16(pa, vb, acc_o[hf]);
      }
    }
  }
  #pragma unroll
  for (int hf = 0; hf < 8; hf++)
    #pragma unroll
    for (int j = 0; j < 4; j++) {
      int t = qt * 64 + w * 16 + lk * 4 + j;
      float val = acc_o[hf][j] / den[j];
      attn_o[((size_t)(b * TT + t)) * (NHQ * HDM) + n * HDM + hf * 16 + lr] = f2bf(val);
    }
}

// ---------------------------------------------------------------------------
extern "C" void kernel_launch(void* const* d_in, const int* in_sizes, int n_in,
                              void* d_out, int out_size, void* d_ws,
                              size_t ws_size, hipStream_t stream) {
  const float* x_img = (const float*)d_in[0];
  const float* x_txt = (const float*)d_in[1];
  const float* sc_attn_i = (const float*)d_in[3];
  const float* wq_i = (const float*)d_in[4];
  const float* wk_i = (const float*)d_in[5];
  const float* wv_i = (const float*)d_in[6];
  const float* wo_i = (const float*)d_in[7];
  const float* sc_ffw_i = (const float*)d_in[8];
  const float* wg_i = (const float*)d_in[9];
  const float* wu_i = (const float*)d_in[10];
  const float* wd_i = (const float*)d_in[11];
  const float* sc_attn_t = (const float*)d_in[12];
  const float* wq_t = (const float*)d_in[13];
  const float* wk_t = (const float*)d_in[14];
  const float* wv_t = (const float*)d_in[15];
  const float* wo_t = (const float*)d_in[16];
  const float* sc_ffw_t = (const float*)d_in[17];
  const float* wg_t = (const float*)d_in[18];
  const float* wu_t = (const float*)d_in[19];
  const float* wd_t = (const float*)d_in[20];
  float* outp = (float*)d_out;
  float* outp_t = outp + (size_t)2 * 1024 * 2048;

  char* ws = (char*)d_ws;
  size_t off = 0;
  auto alloc = [&](size_t n) {
    char* p = ws + off;
    off += (n + 255) & ~(size_t)255;
    return p;
  };
  bf16* WqT_i = (bf16*)alloc((size_t)2048 * 2048 * 2);
  bf16* WkT_i = (bf16*)alloc((size_t)1024 * 2048 * 2);
  bf16* WvT_i = (bf16*)alloc((size_t)1024 * 2048 * 2);
  bf16* WoT_i = (bf16*)alloc((size_t)2048 * 2048 * 2);
  bf16* WguT_i = (bf16*)alloc((size_t)16384 * 2048 * 2);  // interleaved gate/up
  bf16* WdT_i = (bf16*)alloc((size_t)2048 * 8192 * 2);
  bf16* WqT_t = (bf16*)alloc((size_t)2048 * 1024 * 2);
  bf16* WkT_t = (bf16*)alloc((size_t)1024 * 1024 * 2);
  bf16* WvT_t = (bf16*)alloc((size_t)1024 * 1024 * 2);
  bf16* WoT_t = (bf16*)alloc((size_t)1024 * 2048 * 2);
  bf16* WguT_t = (bf16*)alloc((size_t)8192 * 1024 * 2);   // interleaved gate/up
  bf16* WdT_t = (bf16*)alloc((size_t)1024 * 4096 * 2);
  bf16* xn_i = (bf16*)alloc((size_t)2048 * 2048 * 2);
  bf16* xn_t = (bf16*)alloc((size_t)1024 * 1024 * 2);
  char* S = (char*)alloc((size_t)112 * 1024 * 1024);
  (void)ws_size;

  const size_t MB = 1024 * 1024;
  // phase A (attention)
  bf16* q_all = (bf16*)S;                  // 12 MB
  bf16* k_all = (bf16*)(S + 12 * MB);      // 6
  bf16* v_all = (bf16*)(S + 18 * MB);      // 6
  bf16* vtr   = (bf16*)(S + 24 * MB);      // 6
  bf16* attn_o= (bf16*)(S + 30 * MB);      // 12 (dead after wo)
  // wo split-K=2 partials (each 20 MB: img f32 16 + txt f32 4); live to rmsnorm2
  float* wp0 = (float*)(S + 42 * MB);
  float* wp1 = (float*)(S + 62 * MB);      // high water 82 MB
  const size_t TXT_OFF = 16 * MB / 4;
  // phase FFN (q/k/v/vtr/attn_o dead)
  bf16* act_i = (bf16*)S;                  // 32 MB
  bf16* act_t = (bf16*)(S + 32 * MB);      // 8 MB
  // down partials (wp region dead after rmsnorm2)
  float* dp1 = (float*)(S + 42 * MB);      // img 16
  float* dp2 = (float*)(S + 58 * MB);      // img 16
  float* dp3 = (float*)(S + 74 * MB);      // img 16
  float* dt1 = (float*)(S + 90 * MB);      // txt 4
  float* dt2 = (float*)(S + 94 * MB);      // txt 4
  float* dt3 = (float*)(S + 98 * MB);      // txt 4 -> 102 MB

  (void)hipFuncSetAttribute(reinterpret_cast<const void*>(gemm8),
                            hipFuncAttributeMaxDynamicSharedMemorySize, 131072);

  // 1. weight transpose/convert (gate/up interleaved: phys = base + n + (n>>7)*128)
  TJobs tj;
  auto setj = [&](int idx, const float* s, bf16* d, int K, int N, int rb, int rl,
                  int rs) {
    tj.j[idx].src = s; tj.j[idx].dst = d; tj.j[idx].K = K; tj.j[idx].N = N;
    tj.j[idx].r_base = rb; tj.j[idx].r_lsh = rl; tj.j[idx].r_skip = rs;
  };
  setj(0, wq_i, WqT_i, 2048, 2048, 0, 30, 0);
  setj(1, wk_i, WkT_i, 2048, 1024, 0, 30, 0);
  setj(2, wv_i, WvT_i, 2048, 1024, 0, 30, 0);
  setj(3, wo_i, WoT_i, 2048, 2048, 0, 30, 0);
  setj(4, wg_i, WguT_i, 2048, 8192, 0, 7, 128);
  setj(5, wu_i, WguT_i, 2048, 8192, 128, 7, 128);
  setj(6, wd_i, WdT_i, 8192, 2048, 0, 30, 0);
  setj(7, wq_t, WqT_t, 1024, 2048, 0, 30, 0);
  setj(8, wk_t, WkT_t, 1024, 1024, 0, 30, 0);
  setj(9, wv_t, WvT_t, 1024, 1024, 0, 30, 0);
  setj(10, wo_t, WoT_t, 2048, 1024, 0, 30, 0);
  setj(11, wg_t, WguT_t, 1024, 4096, 0, 7, 128);
  setj(12, wu_t, WguT_t, 1024, 4096, 128, 7, 128);
  setj(13, wd_t, WdT_t, 4096, 1024, 0, 30, 0);
  tj.cum[0] = 0;
  for (int i = 0; i < 14; i++)
    tj.cum[i + 1] = tj.cum[i] + (tj.j[i].K >> 6) * (tj.j[i].N >> 6);
  wt_transpose<<<tj.cum[14], 256, 0, stream>>>(tj);

  // 2. pre-attn RMSNorm
  rmsnorm_k<2><<<2048, 256, 0, stream>>>(x_img, sc_attn_i, xn_i);
  rmsnorm_k<1><<<1024, 256, 0, stream>>>(x_txt, sc_attn_t, xn_t);

  auto mk8b = [](const bf16* A, const bf16* B, bf16* Cb, int K, int N, int lda,
                 int ldb, int ab, int ash, int ask, int cb2, int csh, int csk,
                 int cstr, int fuse) {
    G8Job g{};
    g.A = A; g.B = B; g.Cb = Cb; g.Cf = nullptr;
    g.K = K; g.N = N; g.lda = lda; g.ldb = ldb;
    g.a_base = ab; g.a_lsh = ash; g.a_lskip = ask;
    g.c_base = cb2; g.c_lsh = csh; g.c_lskip = csk; g.c_stride = cstr;
    g.fuse = fuse;
    return g;
  };
  auto mk8f = [](const bf16* A, const bf16* B, float* Cf, int K, int N, int lda,
                 int ldb, int ab, int ash, int ask, int cstr) {
    G8Job g{};
    g.A = A; g.B = B; g.Cb = nullptr; g.Cf = Cf;
    g.K = K; g.N = N; g.lda = lda; g.ldb = ldb;
    g.a_base = ab; g.a_lsh = ash; g.a_lskip = ask;
    g.c_base = 0; g.c_lsh = 30; g.c_lskip = 0; g.c_stride = cstr;
    g.fuse = 0;
    return g;
  };
  auto launch8 = [&](G8Jobs& P, int nj, const int* Mt) {
    P.nj = nj;
    P.cum[0] = 0;
    for (int i = 0; i < nj; i++) P.cum[i + 1] = P.cum[i] + Mt[i] * (P.j[i].N >> 8);
    gemm8<<<P.cum[nj], 512, 131072, stream>>>(P);
  };

  // 3. QKV via gemm8 (192 blocks; img nk=32 first, txt nk=16)
  {
    G8Jobs P;
    P.j[0] = mk8b(xn_i, WqT_i, q_all, 2048, 2048, 2048, 2048, 0, 30, 0, 0, 10, 512, 2048, 0);
    P.j[1] = mk8b(xn_i, WkT_i, k_all, 2048, 1024, 2048, 2048, 0, 30, 0, 0, 10, 512, 1024, 0);
    P.j[2] = mk8b(xn_i, WvT_i, v_all, 2048, 1024, 2048, 2048, 0, 30, 0, 0, 10, 512, 1024, 0);
    P.j[3] = mk8b(xn_t, WqT_t, q_all, 1024, 2048, 1024, 1024, 0, 30, 0, 1024, 9, 1024, 2048, 0);
    P.j[4] = mk8b(xn_t, WkT_t, k_all, 1024, 1024, 1024, 1024, 0, 30, 0, 1024, 9, 1024, 1024, 0);
    P.j[5] = mk8b(xn_t, WvT_t, v_all, 1024, 1024, 1024, 1024, 0, 30, 0, 1024, 9, 1024, 1024, 0);
    int Mt[6] = {8, 8, 8, 4, 4, 4};
    launch8(P, 6, Mt);
  }

  // 4. RoPE
  rope_inplace<<<12288, 256, 0, stream>>>(q_all, 4, 0.08838834764831845f);
  rope_inplace<<<6144, 256, 0, stream>>>(k_all, 3, 1.0f);

  // 5. V transpose
  transpose_v<<<dim3(24, 2, 16), 256, 0, stream>>>(v_all, vtr);

  // 6. attention
  attn_k<<<dim3(24, 16, 2), 256, 0, stream>>>(q_all, k_all, vtr, attn_o);

  // 7. WO split-K=2 (4 jobs, 160 blocks, uniform nk=16)
  {
    G8Jobs P;
    P.j[0] = mk8f(attn_o,        WoT_i,        wp0, 1024, 2048, 2048, 2048, 0, 10, 512, 2048);
    P.j[1] = mk8f(attn_o + 1024, WoT_i + 1024, wp1, 1024, 2048, 2048, 2048, 0, 10, 512, 2048);
    P.j[2] = mk8f(attn_o,        WoT_t,        wp0 + TXT_OFF, 1024, 1024, 2048, 2048, 1024, 9, 1024, 1024);
    P.j[3] = mk8f(attn_o + 1024, WoT_t + 1024, wp1 + TXT_OFF, 1024, 1024, 2048, 2048, 1024, 9, 1024, 1024);
    int Mt[4] = {8, 8, 4, 4};
    launch8(P, 4, Mt);
  }

  // 8. fused (p0+p1+x) RMSNorm -> xn
  rmsnorm2_k<2><<<2048, 256, 0, stream>>>(wp0, wp1, x_img, sc_ffw_i, xn_i);
  rmsnorm2_k<1><<<1024, 256, 0, stream>>>(wp0 + TXT_OFF, wp1 + TXT_OFF, x_txt,
                                          sc_ffw_t, xn_t);

  // 9. gate|up with fused GELU epilogue -> act (img 512 blocks = 2 clean
  //    rounds; txt 128 blocks)
  {
    G8Jobs P;
    P.j[0] = mk8b(xn_i, WguT_i, act_i, 2048, 16384, 2048, 2048, 0, 30, 0, 0, 30, 0, 8192, 1);
    int Mt[1] = {8};
    launch8(P, 1, Mt);
  }
  {
    G8Jobs P;
    P.j[0] = mk8b(xn_t, WguT_t, act_t, 1024, 8192, 1024, 1024, 0, 30, 0, 0, 30, 0, 4096, 1);
    int Mt[1] = {4};
    launch8(P, 1, Mt);
  }

  // 10. DOWN: img split-4 (256 blocks nk=32, 1 clean round, ordered first)
  //     + txt split-4 (64 blocks nk=16, short round 2); p0 -> d_out
  {
    G8Jobs P;
    P.j[0] = mk8f(act_i,        WdT_i,        outp, 2048, 2048, 8192, 8192, 0, 30, 0, 2048);
    P.j[1] = mk8f(act_i + 2048, WdT_i + 2048, dp1,  2048, 2048, 8192, 8192, 0, 30, 0, 2048);
    P.j[2] = mk8f(act_i + 4096, WdT_i + 4096, dp2,  2048, 2048, 8192, 8192, 0, 30, 0, 2048);
    P.j[3] = mk8f(act_i + 6144, WdT_i + 6144, dp3,  2048, 2048, 8192, 8192, 0, 30, 0, 2048);
    P.j[4] = mk8f(act_t,        WdT_t,        outp_t, 1024, 1024, 4096, 4096, 0, 30, 0, 1024);
    P.j[5] = mk8f(act_t + 1024, WdT_t + 1024, dt1,  1024, 1024, 4096, 4096, 0, 30, 0, 1024);
    P.j[6] = mk8f(act_t + 2048, WdT_t + 2048, dt2,  1024, 1024, 4096, 4096, 0, 30, 0, 1024);
    P.j[7] = mk8f(act_t + 3072, WdT_t + 3072, dt3,  1024, 1024, 4096, 4096, 0, 30, 0, 1024);
    int Mt[8] = {8, 8, 8, 8, 4, 4, 4, 4};
    launch8(P, 8, Mt);
  }
  reduce_down<<<2048, 256, 0, stream>>>(outp, dp1, dp2, dp3, x_img, 2048 * 2048 / 4,
                                        outp_t, dt1, dt2, dt3, x_txt, 1024 * 1024 / 4);
}

// Round 8
// 646.097 us; speedup vs baseline: 1.0805x; 1.0805x over previous
//
#include <hip/hip_runtime.h>
#include <hip/hip_bf16.h>

// MoE (img/txt mixture) transformer block for MI355X.
// Round 8: revert to r5 structure (best: 665us) + two clean deltas:
//  (a) wo split-K reduce fused into rmsnorm2 (p0+p1+x -> norm), reduce pass gone
//  (b) down split-K=4 img (256 blocks, 1 clean round) + split-K=4 txt (64),
//      partials over dead WguT region (re-transposed every call).

typedef __hip_bfloat16 bf16;
typedef __attribute__((ext_vector_type(8))) __bf16 bf16x8;
typedef __attribute__((ext_vector_type(4))) float f32x4;

#define DEV __device__ __forceinline__

static constexpr int TT = 1536;
static constexpr int NHQ = 16, NKVH = 8, HDM = 128;

DEV void async_load16(const void* g, void* l) {
  typedef const __attribute__((address_space(1))) void* gas_t;
  typedef __attribute__((address_space(3))) void* las_t;
  __builtin_amdgcn_global_load_lds((gas_t)g, (las_t)l, 16, 0, 0);
}

DEV f32x4 mfma16(bf16x8 a, bf16x8 b, f32x4 c) {
  return __builtin_amdgcn_mfma_f32_16x16x32_bf16(a, b, c, 0, 0, 0);
}

DEV float bf2f(bf16 x) { return __bfloat162float(x); }
DEV bf16  f2bf(float x) { return __float2bfloat16(x); }

// ---------------------------------------------------------------------------
// Weight transpose+convert: f32 [K][N] -> bf16 [N][K]
// ---------------------------------------------------------------------------
struct TJob { const float* src; bf16* dst; int K; int N; };
struct TJobs { TJob j[14]; int cum[15]; };

__global__ __launch_bounds__(256) void wt_transpose(TJobs P) {
  __shared__ bf16 tile[64][65];
  int bid = blockIdx.x;
  int ji = 0;
  while (ji < 13 && bid >= P.cum[ji + 1]) ji++;
  const TJob jb = P.j[ji];
  int rel = bid - P.cum[ji];
  int ntc = jb.N >> 6;
  int tr = rel / ntc, tc = rel - tr * ntc;
  int r0 = tr << 6, c0 = tc << 6;
  int t = threadIdx.x;
  #pragma unroll
  for (int i = 0; i < 16; i++) {
    int idx = i * 256 + t;
    int r = idx >> 6, c = idx & 63;
    tile[c][r] = f2bf(jb.src[(size_t)(r0 + r) * jb.N + c0 + c]);
  }
  __syncthreads();
  #pragma unroll
  for (int i = 0; i < 16; i++) {
    int idx = i * 256 + t;
    int r = idx >> 6, c = idx & 63;
    jb.dst[(size_t)(c0 + r) * jb.K + r0 + c] = tile[r][c];
  }
}

// bf16 transpose for V: v_all [B*TT][NKVH*HDM] -> vt [B*NKVH][HDM][TT]
__global__ __launch_bounds__(256) void transpose_v(const bf16* __restrict__ v_all,
                                                   bf16* __restrict__ vt) {
  int st = blockIdx.x, ht = blockIdx.y, bk = blockIdx.z;
  int b = bk >> 3, kv = bk & 7;
  __shared__ bf16 tile[64][65];
  int t = threadIdx.x;
  int s0 = st * 64, h0 = ht * 64;
  #pragma unroll
  for (int i = 0; i < 16; i++) {
    int idx = i * 256 + t;
    int r = idx >> 6, c = idx & 63;
    tile[c][r] = v_all[((size_t)(b * TT + s0 + r) * NKVH + kv) * HDM + h0 + c];
  }
  __syncthreads();
  #pragma unroll
  for (int i = 0; i < 16; i++) {
    int idx = i * 256 + t;
    int r = idx >> 6, c = idx & 63;
    vt[((size_t)bk * HDM + h0 + r) * TT + s0 + c] = tile[r][c];
  }
}

// ---------------------------------------------------------------------------
// RMSNorm (single input)
// ---------------------------------------------------------------------------
template <int DV>
__global__ __launch_bounds__(256) void rmsnorm_k(const float* __restrict__ x,
                                                 const float* __restrict__ sc,
                                                 bf16* __restrict__ out) {
  const int D = DV * 1024;
  int row = blockIdx.x, t = threadIdx.x;
  const float4* xr = reinterpret_cast<const float4*>(x + (size_t)row * D);
  float4 v[DV];
  float ss = 0.f;
  #pragma unroll
  for (int i = 0; i < DV; i++) {
    v[i] = xr[t + i * 256];
    ss += v[i].x * v[i].x + v[i].y * v[i].y + v[i].z * v[i].z + v[i].w * v[i].w;
  }
  #pragma unroll
  for (int o = 1; o < 64; o <<= 1) ss += __shfl_xor(ss, o);
  __shared__ float red[4];
  if ((t & 63) == 0) red[t >> 6] = ss;
  __syncthreads();
  float r = rsqrtf((red[0] + red[1] + red[2] + red[3]) * (1.0f / D) + 1e-6f);
  bf16* orow = out + (size_t)row * D;
  #pragma unroll
  for (int i = 0; i < DV; i++) {
    int c = (t + i * 256) * 4;
    orow[c + 0] = f2bf(v[i].x * r * (1.f + sc[c + 0]));
    orow[c + 1] = f2bf(v[i].y * r * (1.f + sc[c + 1]));
    orow[c + 2] = f2bf(v[i].z * r * (1.f + sc[c + 2]));
    orow[c + 3] = f2bf(v[i].w * r * (1.f + sc[c + 3]));
  }
}

// ---------------------------------------------------------------------------
// RMSNorm over (p0+p1+x): fused wo split-K=2 reduce + pre-FFW norm
// ---------------------------------------------------------------------------
template <int DV>
__global__ __launch_bounds__(256) void rmsnorm2_k(
    const float* __restrict__ p0, const float* __restrict__ p1,
    const float* __restrict__ x, const float* __restrict__ sc,
    bf16* __restrict__ out) {
  const int D = DV * 1024;
  int row = blockIdx.x, t = threadIdx.x;
  size_t rb = (size_t)row * (D / 4);
  const float4* r0 = reinterpret_cast<const float4*>(p0) + rb;
  const float4* r1 = reinterpret_cast<const float4*>(p1) + rb;
  const float4* xr = reinterpret_cast<const float4*>(x) + rb;
  float4 v[DV];
  float ss = 0.f;
  #pragma unroll
  for (int i = 0; i < DV; i++) {
    int idx = t + i * 256;
    float4 a = r0[idx], b = r1[idx], e = xr[idx];
    v[i] = make_float4(a.x + b.x + e.x, a.y + b.y + e.y,
                       a.z + b.z + e.z, a.w + b.w + e.w);
    ss += v[i].x * v[i].x + v[i].y * v[i].y + v[i].z * v[i].z + v[i].w * v[i].w;
  }
  #pragma unroll
  for (int o = 1; o < 64; o <<= 1) ss += __shfl_xor(ss, o);
  __shared__ float red[4];
  if ((t & 63) == 0) red[t >> 6] = ss;
  __syncthreads();
  float r = rsqrtf((red[0] + red[1] + red[2] + red[3]) * (1.0f / D) + 1e-6f);
  bf16* orow = out + (size_t)row * D;
  #pragma unroll
  for (int i = 0; i < DV; i++) {
    int c = (t + i * 256) * 4;
    orow[c + 0] = f2bf(v[i].x * r * (1.f + sc[c + 0]));
    orow[c + 1] = f2bf(v[i].y * r * (1.f + sc[c + 1]));
    orow[c + 2] = f2bf(v[i].z * r * (1.f + sc[c + 2]));
    orow[c + 3] = f2bf(v[i].w * r * (1.f + sc[c + 3]));
  }
}

// ---------------------------------------------------------------------------
// RoPE in-place
// ---------------------------------------------------------------------------
__global__ __launch_bounds__(256) void rope_inplace(bf16* __restrict__ x, int lognh,
                                                    float scale) {
  int gid = blockIdx.x * 256 + threadIdx.x;
  int i = gid & 63;
  int rh = gid >> 6;
  int row = rh >> lognh;
  int pos = row >= TT ? row - TT : row;
  float fr = expf(-9.210340371976184f * ((float)(2 * i) * (1.0f / 128.0f)));
  float th = (float)pos * fr;
  float s, c;
  sincosf(th, &s, &c);
  bf16* p = x + (size_t)rh * HDM;
  float x1 = bf2f(p[i]), x2 = bf2f(p[i + 64]);
  p[i]      = f2bf((x1 * c - x2 * s) * scale);
  p[i + 64] = f2bf((x2 * c + x1 * s) * scale);
}

// ---------------------------------------------------------------------------
// 8-phase 256x256 GEMM (T2+T3+T4+T5) - proven r4/r5 K-loop, unchanged.
// ---------------------------------------------------------------------------
struct G8Job {
  const bf16* A; const bf16* B; bf16* Cb; float* Cf;
  int K, N, lda, ldb;
  int a_base, a_lsh, a_lskip;
  int c_base, c_lsh, c_lskip, c_stride;
};
struct G8Jobs { G8Job j[8]; int cum[9]; int nj; };

#define G8_BAR_MFMA(MH, NH)                                        \
  __builtin_amdgcn_s_barrier();                                    \
  asm volatile("s_waitcnt lgkmcnt(0)" ::: "memory");               \
  __builtin_amdgcn_sched_barrier(0);                               \
  __builtin_amdgcn_s_setprio(1);                                   \
  _Pragma("unroll")                                                \
  for (int i = 0; i < 4; i++)                                      \
    _Pragma("unroll")                                              \
    for (int nj2 = 0; nj2 < 2; nj2++)                              \
      _Pragma("unroll")                                            \
      for (int kk = 0; kk < 2; kk++)                               \
        acc[(MH)*4 + i][(NH)*2 + nj2] = mfma16(                    \
            afr[i][kk], bfr[(NH)*2 + nj2][kk],                     \
            acc[(MH)*4 + i][(NH)*2 + nj2]);                        \
  __builtin_amdgcn_s_setprio(0);                                   \
  __builtin_amdgcn_s_barrier();                                    \
  asm volatile("" ::: "memory");

__global__ __launch_bounds__(512, 2) void gemm8(G8Jobs P) {
  extern __shared__ __align__(16) bf16 lds8[];
  int bid = blockIdx.x;
  int ji = 0;
  while (ji < P.nj - 1 && bid >= P.cum[ji + 1]) ji++;
  const G8Job jb = P.j[ji];
  int rel = bid - P.cum[ji];
  int tn = jb.N >> 8;
  int bm = rel / tn, bn = rel - bm * tn;
  const int m0 = bm << 8, n0 = bn << 8;
  const int K = jb.K;
  const int nk = K >> 6;

  const int tid = threadIdx.x;
  const int w = tid >> 6, l = tid & 63;
  const int lr = l & 15, lk = l >> 4;
  const int wr = w >> 2, wc = w & 3;

  const int r0 = tid >> 3, sl0 = (tid & 7) ^ (r0 & 7);
  const int dst0 = (w * 64) * 8;
  const int dst1 = (512 + w * 64) * 8;

  auto stage = [&](int ht, int hq) {
    int k0 = ht << 6;
    bf16* ldsb = lds8 + ((ht & 1) * 32768 + hq * 8192);
    if (hq < 2) {
      int ma = m0 + hq * 128;
      int mr0 = ma + r0, mr1 = ma + 64 + r0;
      int pr0 = jb.a_base + mr0 + ((mr0 >> jb.a_lsh) * jb.a_lskip);
      int pr1 = jb.a_base + mr1 + ((mr1 >> jb.a_lsh) * jb.a_lskip);
      async_load16(jb.A + (size_t)pr0 * jb.lda + k0 + sl0 * 8, ldsb + dst0);
      async_load16(jb.A + (size_t)pr1 * jb.lda + k0 + sl0 * 8, ldsb + dst1);
    } else {
      int nb = n0 + (hq - 2) * 128;
      async_load16(jb.B + (size_t)(nb + r0) * jb.ldb + k0 + sl0 * 8, ldsb + dst0);
      async_load16(jb.B + (size_t)(nb + 64 + r0) * jb.ldb + k0 + sl0 * 8, ldsb + dst1);
    }
  };

  f32x4 acc[8][4];
  #pragma unroll
  for (int i = 0; i < 8; i++)
    #pragma unroll
    for (int j = 0; j < 4; j++) acc[i][j] = (f32x4){0.f, 0.f, 0.f, 0.f};

  const int s0 = ((0 * 4 + lk) ^ (lr & 7)) * 8;
  const int s1 = ((1 * 4 + lk) ^ (lr & 7)) * 8;
  const int browb = (wc & 1) * 64;

  #pragma unroll
  for (int hq = 0; hq < 4; hq++) stage(0, hq);
  #pragma unroll
  for (int hq = 0; hq < 4; hq++) stage(1, hq);
  asm volatile("s_waitcnt vmcnt(8)" ::: "memory");
  __builtin_amdgcn_s_barrier();
  asm volatile("" ::: "memory");

  bf16x8 afr[4][2], bfr[4][2];

  for (int t = 0; t < nk; t++) {
    const bf16* bufA = lds8 + (t & 1) * 32768 + wr * 8192;
    const bf16* bufB = lds8 + (t & 1) * 32768 + 16384 + (wc >> 1) * 8192;
    const bool st = (t + 2 < nk);

    #pragma unroll
    for (int i = 0; i < 4; i++) {
      int rb = (i * 16 + lr) * 64;
      afr[i][0] = *reinterpret_cast<const bf16x8*>(bufA + rb + s0);
      afr[i][1] = *reinterpret_cast<const bf16x8*>(bufA + rb + s1);
    }
    #pragma unroll
    for (int ni = 0; ni < 2; ni++) {
      int rb = (browb + ni * 16 + lr) * 64;
      bfr[ni][0] = *reinterpret_cast<const bf16x8*>(bufB + rb + s0);
      bfr[ni][1] = *reinterpret_cast<const bf16x8*>(bufB + rb + s1);
    }
    G8_BAR_MFMA(0, 0)

    #pragma unroll
    for (int ni = 2; ni < 4; ni++) {
      int rb = (browb + ni * 16 + lr) * 64;
      bfr[ni][0] = *reinterpret_cast<const bf16x8*>(bufB + rb + s0);
      bfr[ni][1] = *reinterpret_cast<const bf16x8*>(bufB + rb + s1);
    }
    G8_BAR_MFMA(0, 1)

    #pragma unroll
    for (int i = 0; i < 4; i++) {
      int rb = ((i + 4) * 16 + lr) * 64;
      afr[i][0] = *reinterpret_cast<const bf16x8*>(bufA + rb + s0);
      afr[i][1] = *reinterpret_cast<const bf16x8*>(bufA + rb + s1);
    }
    if (st) { stage(t + 2, 2); stage(t + 2, 3); }
    G8_BAR_MFMA(1, 0)

    if (st) {
      stage(t + 2, 0); stage(t + 2, 1);
      asm volatile("s_waitcnt vmcnt(8)" ::: "memory");
    } else if (t == nk - 2) {
      asm volatile("s_waitcnt vmcnt(0)" ::: "memory");
    }
    G8_BAR_MFMA(1, 1)
  }

  if (jb.Cf) {
    #pragma unroll
    for (int mi = 0; mi < 8; mi++)
      #pragma unroll
      for (int jj = 0; jj < 4; jj++) {
        int m = m0 + wr * 128 + mi * 16 + lk * 4 + jj;
        float* drow = jb.Cf + (size_t)m * jb.c_stride + n0 + wc * 64;
        #pragma unroll
        for (int ni = 0; ni < 4; ni++) drow[ni * 16 + lr] = acc[mi][ni][jj];
      }
  } else {
    #pragma unroll
    for (int mi = 0; mi < 8; mi++)
      #pragma unroll
      for (int jj = 0; jj < 4; jj++) {
        int m = m0 + wr * 128 + mi * 16 + lk * 4 + jj;
        int crow = jb.c_base + m + ((m >> jb.c_lsh) * jb.c_lskip);
        bf16* drow = jb.Cb + (size_t)crow * jb.c_stride + n0 + wc * 64;
        #pragma unroll
        for (int ni = 0; ni < 4; ni++) drow[ni * 16 + lr] = f2bf(acc[mi][ni][jj]);
      }
  }
}

// ---------------------------------------------------------------------------
// Down split-K reduce: out += p1+p2+p3+x for img and txt
// ---------------------------------------------------------------------------
__global__ __launch_bounds__(256) void reduce_down(
    float* __restrict__ oi, const float* __restrict__ a1,
    const float* __restrict__ a2, const float* __restrict__ a3,
    const float* __restrict__ xi, int n4i,
    float* __restrict__ ot, const float* __restrict__ b1,
    const float* __restrict__ b2, const float* __restrict__ b3,
    const float* __restrict__ xt, int n4t) {
  int tot = n4i + n4t;
  for (int idx = blockIdx.x * 256 + threadIdx.x; idx < tot; idx += gridDim.x * 256) {
    if (idx < n4i) {
      float4 d = ((const float4*)oi)[idx];
      float4 a = ((const float4*)a1)[idx];
      float4 b = ((const float4*)a2)[idx];
      float4 c = ((const float4*)a3)[idx];
      float4 e = ((const float4*)xi)[idx];
      ((float4*)oi)[idx] = make_float4(d.x + a.x + b.x + c.x + e.x,
                                       d.y + a.y + b.y + c.y + e.y,
                                       d.z + a.z + b.z + c.z + e.z,
                                       d.w + a.w + b.w + c.w + e.w);
    } else {
      int i = idx - n4i;
      float4 d = ((const float4*)ot)[i];
      float4 a = ((const float4*)b1)[i];
      float4 b = ((const float4*)b2)[i];
      float4 c = ((const float4*)b3)[i];
      float4 e = ((const float4*)xt)[i];
      ((float4*)ot)[i] = make_float4(d.x + a.x + b.x + c.x + e.x,
                                     d.y + a.y + b.y + c.y + e.y,
                                     d.z + a.z + b.z + c.z + e.z,
                                     d.w + a.w + b.w + c.w + e.w);
    }
  }
}

// ---------------------------------------------------------------------------
// In-place GELU(gate)*up over gu buffers: act written to gate half.
// ---------------------------------------------------------------------------
__global__ __launch_bounds__(256) void gelu_mul(bf16* __restrict__ gu_i,
                                                bf16* __restrict__ gu_t) {
  const int IMG_CH = 2048 * 8192 / 8;
  const int TXT_CH = 1024 * 4096 / 8;
  int idx = blockIdx.x * 256 + threadIdx.x;
  int total = IMG_CH + TXT_CH;
  if (idx >= total) return;
  bf16* base;
  int half, ci;
  if (idx < IMG_CH) { base = gu_i; half = 8192; ci = idx; }
  else              { base = gu_t; half = 4096; ci = idx - IMG_CH; }
  int rowlen = half * 2;
  int perrow = half / 8;
  int m = ci / perrow, n8 = ci - m * perrow;
  bf16* gp = base + (size_t)m * rowlen + n8 * 8;
  bf16* up = gp + half;
  bf16x8 g8 = *reinterpret_cast<const bf16x8*>(gp);
  bf16x8 u8 = *reinterpret_cast<const bf16x8*>(up);
  bf16x8 o8;
  #pragma unroll
  for (int i = 0; i < 8; i++) {
    float g = (float)g8[i], u = (float)u8[i];
    float t = tanhf(0.7978845608028654f * (g + 0.044715f * g * g * g));
    o8[i] = (__bf16)(0.5f * g * (1.f + t) * u);
  }
  *reinterpret_cast<bf16x8*>(gp) = o8;
}

// ---------------------------------------------------------------------------
// Flash attention with softcap (no online max; logits bounded by +-50).
// ---------------------------------------------------------------------------
__global__ __launch_bounds__(256) void attn_k(const bf16* __restrict__ q_all,
                                              const bf16* __restrict__ k_all,
                                              const bf16* __restrict__ vt,
                                              bf16* __restrict__ attn_o) {
  const int qt = blockIdx.x;
  const int n = blockIdx.y;
  const int b = blockIdx.z;
  const int kv = n >> 1;
  const int tid = threadIdx.x, w = tid >> 6, l = tid & 63;
  const int lr = l & 15, lk = l >> 4;
  __shared__ __align__(16) bf16 Ksm[64 * 128];
  __shared__ __align__(16) bf16 Vsm[128 * 64];
  __shared__ __align__(16) bf16 Psm[4][16][72];

  bf16x8 qf[4];
  {
    int t = qt * 64 + w * 16 + lr;
    const bf16* qp = q_all + ((size_t)(b * TT + t) * NHQ + n) * HDM;
    #pragma unroll
    for (int kk = 0; kk < 4; kk++)
      qf[kk] = *reinterpret_cast<const bf16x8*>(qp + kk * 32 + lk * 8);
  }
  f32x4 acc_o[8];
  #pragma unroll
  for (int i = 0; i < 8; i++) acc_o[i] = (f32x4){0.f, 0.f, 0.f, 0.f};
  float den[4] = {0.f, 0.f, 0.f, 0.f};

  for (int st = 0; st < TT / 64; st++) {
    __syncthreads();
    #pragma unroll
    for (int i = 0; i < 4; i++) {
      int cb = (w * 4 + i) * 64;
      int c = cb + l;
      {
        int srow = c >> 4, c16 = c & 15;
        const bf16* g = k_all + ((size_t)(b * TT + st * 64 + srow) * NKVH + kv) * HDM +
                        ((c16 ^ (srow & 7)) << 3);
        async_load16(g, Ksm + cb * 8);
      }
      {
        int hrow = c >> 3, c8 = c & 7;
        const bf16* g = vt + ((size_t)(b * NKVH + kv) * HDM + hrow) * TT + st * 64 +
                        ((c8 ^ (hrow & 7)) << 3);
        async_load16(g, Vsm + cb * 8);
      }
    }
    __syncthreads();
    #pragma unroll
    for (int sf = 0; sf < 4; sf++) {
      f32x4 s4 = (f32x4){0.f, 0.f, 0.f, 0.f};
      int sl = sf * 16 + lr;
      #pragma unroll
      for (int kk = 0; kk < 4; kk++) {
        int e = kk * 32 + lk * 8;
        bf16x8 kf = *reinterpret_cast<const bf16x8*>(
            Ksm + sl * 128 + ((((e >> 3) ^ (sl & 7))) << 3));
        s4 = mfma16(qf[kk], kf, s4);
      }
      #pragma unroll
      for (int j = 0; j < 4; j++) {
        float xv = s4[j];
        float tcap = tanhf(xv * 0.02f) * 50.f;
        float p = __expf(tcap);
        Psm[w][lk * 4 + j][sf * 16 + lr] = f2bf(p);
        p += __shfl_xor(p, 1);
        p += __shfl_xor(p, 2);
        p += __shfl_xor(p, 4);
        p += __shfl_xor(p, 8);
        den[j] += p;
      }
    }
    #pragma unroll
    for (int kk2 = 0; kk2 < 2; kk2++) {
      bf16x8 pa = *reinterpret_cast<const bf16x8*>(&Psm[w][lr][kk2 * 32 + lk * 8]);
      #pragma unroll
      for (int hf = 0; hf < 8; hf++) {
        int h = hf * 16 + lr;
        int e2 = kk2 * 32 + lk * 8;
        bf16x8 vb = *reinterpret_cast<const bf16x8*>(
            Vsm + h * 64 + ((((e2 >> 3) ^ (h & 7))) << 3));
        acc_o[hf] = mfma16(pa, vb, acc_o[hf]);
      }
    }
  }
  #pragma unroll
  for (int hf = 0; hf < 8; hf++)
    #pragma unroll
    for (int j = 0; j < 4; j++) {
      int t = qt * 64 + w * 16 + lk * 4 + j;
      float val = acc_o[hf][j] / den[j];
      attn_o[((size_t)(b * TT + t)) * (NHQ * HDM) + n * HDM + hf * 16 + lr] = f2bf(val);
    }
}

// ---------------------------------------------------------------------------
extern "C" void kernel_launch(void* const* d_in, const int* in_sizes, int n_in,
                              void* d_out, int out_size, void* d_ws,
                              size_t ws_size, hipStream_t stream) {
  const float* x_img = (const float*)d_in[0];
  const float* x_txt = (const float*)d_in[1];
  const float* sc_attn_i = (const float*)d_in[3];
  const float* wq_i = (const float*)d_in[4];
  const float* wk_i = (const float*)d_in[5];
  const float* wv_i = (const float*)d_in[6];
  const float* wo_i = (const float*)d_in[7];
  const float* sc_ffw_i = (const float*)d_in[8];
  const float* wg_i = (const float*)d_in[9];
  const float* wu_i = (const float*)d_in[10];
  const float* wd_i = (const float*)d_in[11];
  const float* sc_attn_t = (const float*)d_in[12];
  const float* wq_t = (const float*)d_in[13];
  const float* wk_t = (const float*)d_in[14];
  const float* wv_t = (const float*)d_in[15];
  const float* wo_t = (const float*)d_in[16];
  const float* sc_ffw_t = (const float*)d_in[17];
  const float* wg_t = (const float*)d_in[18];
  const float* wu_t = (const float*)d_in[19];
  const float* wd_t = (const float*)d_in[20];
  float* outp = (float*)d_out;
  float* outp_t = outp + (size_t)2 * 1024 * 2048;

  char* ws = (char*)d_ws;
  size_t off = 0;
  auto alloc = [&](size_t n) {
    char* p = ws + off;
    off += (n + 255) & ~(size_t)255;
    return p;
  };
  bf16* WqT_i = (bf16*)alloc((size_t)2048 * 2048 * 2);
  bf16* WkT_i = (bf16*)alloc((size_t)1024 * 2048 * 2);
  bf16* WvT_i = (bf16*)alloc((size_t)1024 * 2048 * 2);
  bf16* WoT_i = (bf16*)alloc((size_t)2048 * 2048 * 2);
  bf16* WguT_i = (bf16*)alloc((size_t)16384 * 2048 * 2);  // gate rows 0..8191, up 8192..
  bf16* WdT_i = (bf16*)alloc((size_t)2048 * 8192 * 2);
  bf16* WqT_t = (bf16*)alloc((size_t)2048 * 1024 * 2);
  bf16* WkT_t = (bf16*)alloc((size_t)1024 * 1024 * 2);
  bf16* WvT_t = (bf16*)alloc((size_t)1024 * 1024 * 2);
  bf16* WoT_t = (bf16*)alloc((size_t)1024 * 2048 * 2);
  bf16* WguT_t = (bf16*)alloc((size_t)8192 * 1024 * 2);
  bf16* WdT_t = (bf16*)alloc((size_t)1024 * 4096 * 2);
  bf16* xn_i = (bf16*)alloc((size_t)2048 * 2048 * 2);   // 8 MB
  bf16* xn_t = (bf16*)alloc((size_t)1024 * 1024 * 2);   // 2 MB
  float* h_i = (float*)alloc((size_t)2048 * 2048 * 4);  // 16 MB (wo p0 img)
  float* h_t = (float*)alloc((size_t)1024 * 1024 * 4);  // 4 MB  (wo p0 txt)
  char* S = (char*)alloc((size_t)84 * 1024 * 1024);
  (void)ws_size;

  const size_t MB = 1024 * 1024;
  // phase A (attention) layout in S
  bf16* q_all = (bf16*)S;
  bf16* k_all = (bf16*)(S + 12 * MB);
  bf16* v_all = (bf16*)(S + 18 * MB);
  bf16* vtr   = (bf16*)(S + 24 * MB);
  bf16* attn_o= (bf16*)(S + 30 * MB);      // live through wo
  // wo split-K=2 p1 partials over dead q/k region
  float* wp1_i = (float*)S;                // 16 MB
  float* wp1_t = (float*)(S + 16 * MB);    // 4 MB
  // phase FFN
  bf16* gu_i  = (bf16*)S;                  // 64 MB
  bf16* gu_t  = (bf16*)(S + 64 * MB);      // 16 MB
  // down partials over dead WguT region (re-transposed every call -> replay-safe)
  float* dp1 = (float*)WguT_i;                       // img 16 MB
  float* dp2 = (float*)((char*)WguT_i + 16 * MB);    // img 16 MB
  float* dp3 = (float*)((char*)WguT_i + 32 * MB);    // img 16 MB
  float* dt1 = (float*)WguT_t;                       // txt 4 MB
  float* dt2 = (float*)((char*)WguT_t + 4 * MB);     // txt 4 MB
  float* dt3 = (float*)((char*)WguT_t + 8 * MB);     // txt 4 MB

  (void)hipFuncSetAttribute(reinterpret_cast<const void*>(gemm8),
                            hipFuncAttributeMaxDynamicSharedMemorySize, 131072);

  // 1. weight transpose/convert
  TJobs tj;
  auto setj = [&](int idx, const float* s, bf16* d, int K, int N) {
    tj.j[idx].src = s; tj.j[idx].dst = d; tj.j[idx].K = K; tj.j[idx].N = N;
  };
  setj(0, wq_i, WqT_i, 2048, 2048);
  setj(1, wk_i, WkT_i, 2048, 1024);
  setj(2, wv_i, WvT_i, 2048, 1024);
  setj(3, wo_i, WoT_i, 2048, 2048);
  setj(4, wg_i, WguT_i, 2048, 8192);
  setj(5, wu_i, WguT_i + (size_t)8192 * 2048, 2048, 8192);
  setj(6, wd_i, WdT_i, 8192, 2048);
  setj(7, wq_t, WqT_t, 1024, 2048);
  setj(8, wk_t, WkT_t, 1024, 1024);
  setj(9, wv_t, WvT_t, 1024, 1024);
  setj(10, wo_t, WoT_t, 2048, 1024);
  setj(11, wg_t, WguT_t, 1024, 4096);
  setj(12, wu_t, WguT_t + (size_t)4096 * 1024, 1024, 4096);
  setj(13, wd_t, WdT_t, 4096, 1024);
  tj.cum[0] = 0;
  for (int i = 0; i < 14; i++)
    tj.cum[i + 1] = tj.cum[i] + (tj.j[i].K >> 6) * (tj.j[i].N >> 6);
  wt_transpose<<<tj.cum[14], 256, 0, stream>>>(tj);

  // 2. pre-attn RMSNorm
  rmsnorm_k<2><<<2048, 256, 0, stream>>>(x_img, sc_attn_i, xn_i);
  rmsnorm_k<1><<<1024, 256, 0, stream>>>(x_txt, sc_attn_t, xn_t);

  auto mk8b = [](const bf16* A, const bf16* B, bf16* Cb, int K, int N, int lda,
                 int ldb, int ab, int ash, int ask, int cb2, int csh, int csk,
                 int cstr) {
    G8Job g{};
    g.A = A; g.B = B; g.Cb = Cb; g.Cf = nullptr;
    g.K = K; g.N = N; g.lda = lda; g.ldb = ldb;
    g.a_base = ab; g.a_lsh = ash; g.a_lskip = ask;
    g.c_base = cb2; g.c_lsh = csh; g.c_lskip = csk; g.c_stride = cstr;
    return g;
  };
  auto mk8f = [](const bf16* A, const bf16* B, float* Cf, int K, int N, int lda,
                 int ldb, int ab, int ash, int ask, int cstr) {
    G8Job g{};
    g.A = A; g.B = B; g.Cb = nullptr; g.Cf = Cf;
    g.K = K; g.N = N; g.lda = lda; g.ldb = ldb;
    g.a_base = ab; g.a_lsh = ash; g.a_lskip = ask;
    g.c_base = 0; g.c_lsh = 30; g.c_lskip = 0; g.c_stride = cstr;
    return g;
  };
  auto launch8 = [&](G8Jobs& P, int nj, const int* Mt) {
    P.nj = nj;
    P.cum[0] = 0;
    for (int i = 0; i < nj; i++) P.cum[i + 1] = P.cum[i] + Mt[i] * (P.j[i].N >> 8);
    gemm8<<<P.cum[nj], 512, 131072, stream>>>(P);
  };

  // 3. QKV via gemm8
  {
    G8Jobs P;
    P.j[0] = mk8b(xn_i, WqT_i, q_all, 2048, 2048, 2048, 2048, 0, 30, 0, 0, 10, 512, 2048);
    P.j[1] = mk8b(xn_i, WkT_i, k_all, 2048, 1024, 2048, 2048, 0, 30, 0, 0, 10, 512, 1024);
    P.j[2] = mk8b(xn_i, WvT_i, v_all, 2048, 1024, 2048, 2048, 0, 30, 0, 0, 10, 512, 1024);
    P.j[3] = mk8b(xn_t, WqT_t, q_all, 1024, 2048, 1024, 1024, 0, 30, 0, 1024, 9, 1024, 2048);
    P.j[4] = mk8b(xn_t, WkT_t, k_all, 1024, 1024, 1024, 1024, 0, 30, 0, 1024, 9, 1024, 1024);
    P.j[5] = mk8b(xn_t, WvT_t, v_all, 1024, 1024, 1024, 1024, 0, 30, 0, 1024, 9, 1024, 1024);
    int Mt[6] = {8, 8, 8, 4, 4, 4};
    launch8(P, 6, Mt);
  }

  // 4. RoPE
  rope_inplace<<<12288, 256, 0, stream>>>(q_all, 4, 0.08838834764831845f);
  rope_inplace<<<6144, 256, 0, stream>>>(k_all, 3, 1.0f);

  // 5. V transpose
  transpose_v<<<dim3(24, 2, 16), 256, 0, stream>>>(v_all, vtr);

  // 6. attention
  attn_k<<<dim3(24, 16, 2), 256, 0, stream>>>(q_all, k_all, vtr, attn_o);

  // 7. WO split-K=2 (160 blocks): p0 -> h, p1 -> wp1
  {
    G8Jobs P;
    P.j[0] = mk8f(attn_o,        WoT_i,        h_i,   1024, 2048, 2048, 2048, 0, 10, 512, 2048);
    P.j[1] = mk8f(attn_o + 1024, WoT_i + 1024, wp1_i, 1024, 2048, 2048, 2048, 0, 10, 512, 2048);
    P.j[2] = mk8f(attn_o,        WoT_t,        h_t,   1024, 1024, 2048, 2048, 1024, 9, 1024, 1024);
    P.j[3] = mk8f(attn_o + 1024, WoT_t + 1024, wp1_t, 1024, 1024, 2048, 2048, 1024, 9, 1024, 1024);
    int Mt[4] = {8, 8, 4, 4};
    launch8(P, 4, Mt);
  }

  // 8. fused (p0+p1+x) RMSNorm -> xn (reduce pass eliminated)
  rmsnorm2_k<2><<<2048, 256, 0, stream>>>(h_i, wp1_i, x_img, sc_ffw_i, xn_i);
  rmsnorm2_k<1><<<1024, 256, 0, stream>>>(h_t, wp1_t, x_txt, sc_ffw_t, xn_t);

  // 9. gate|up via gemm8 -> gu (bf16), single launch (640 blocks)
  {
    G8Jobs P;
    P.j[0] = mk8b(xn_i, WguT_i, gu_i, 2048, 16384, 2048, 2048, 0, 30, 0, 0, 30, 0, 16384);
    P.j[1] = mk8b(xn_t, WguT_t, gu_t, 1024, 8192, 1024, 1024, 0, 30, 0, 0, 30, 0, 8192);
    int Mt[2] = {8, 4};
    launch8(P, 2, Mt);
  }
  {
    int total = 2048 * 8192 / 8 + 1024 * 4096 / 8;
    gelu_mul<<<(total + 255) / 256, 256, 0, stream>>>(gu_i, gu_t);
  }

  // 10. DOWN: img split-4 (256 blocks nk=32, clean round 1) + txt split-4
  //     (64 blocks nk=16, round 2). p0 -> d_out; partials over dead WguT.
  {
    G8Jobs P;
    P.j[0] = mk8f(gu_i,        WdT_i,        outp, 2048, 2048, 16384, 8192, 0, 30, 0, 2048);
    P.j[1] = mk8f(gu_i + 2048, WdT_i + 2048, dp1,  2048, 2048, 16384, 8192, 0, 30, 0, 2048);
    P.j[2] = mk8f(gu_i + 4096, WdT_i + 4096, dp2,  2048, 2048, 16384, 8192, 0, 30, 0, 2048);
    P.j[3] = mk8f(gu_i + 6144, WdT_i + 6144, dp3,  2048, 2048, 16384, 8192, 0, 30, 0, 2048);
    P.j[4] = mk8f(gu_t,        WdT_t,        outp_t, 1024, 1024, 8192, 4096, 0, 30, 0, 1024);
    P.j[5] = mk8f(gu_t + 1024, WdT_t + 1024, dt1,  1024, 1024, 8192, 4096, 0, 30, 0, 1024);
    P.j[6] = mk8f(gu_t + 2048, WdT_t + 2048, dt2,  1024, 1024, 8192, 4096, 0, 30, 0, 1024);
    P.j[7] = mk8f(gu_t + 3072, WdT_t + 3072, dt3,  1024, 1024, 8192, 4096, 0, 30, 0, 1024);
    int Mt[8] = {8, 8, 8, 8, 4, 4, 4, 4};
    launch8(P, 8, Mt);
  }
  reduce_down<<<2048, 256, 0, stream>>>(outp, dp1, dp2, dp3, x_img, 2048 * 2048 / 4,
                                        outp_t, dt1, dt2, dt3, x_txt, 1024 * 1024 / 4);
}

// Round 9
// 622.136 us; speedup vs baseline: 1.1221x; 1.0385x over previous
//
#include <hip/hip_runtime.h>
#include <hip/hip_bf16.h>

// MoE (img/txt mixture) transformer block for MI355X.
// Round 9: r8 structure + (a) reduced-barrier gemm8 K-loop (3 barriers/tile:
// after q1 [B slots retire], q2 [A slots retire], q3 [tile boundary+vmcnt]);
// hazard proof: RAW globalized at t-1 q3 vmcnt(8)+barrier; q2 stages B of t+2
// after q1-bar, q3 stages A after q2-bar. (b) down-txt split-K=8 (128 blocks
// nk=8, 2nd launch) -> shorter round 2; reduce takes 7 txt partials.

typedef __hip_bfloat16 bf16;
typedef __attribute__((ext_vector_type(8))) __bf16 bf16x8;
typedef __attribute__((ext_vector_type(4))) float f32x4;

#define DEV __device__ __forceinline__

static constexpr int TT = 1536;
static constexpr int NHQ = 16, NKVH = 8, HDM = 128;

DEV void async_load16(const void* g, void* l) {
  typedef const __attribute__((address_space(1))) void* gas_t;
  typedef __attribute__((address_space(3))) void* las_t;
  __builtin_amdgcn_global_load_lds((gas_t)g, (las_t)l, 16, 0, 0);
}

DEV f32x4 mfma16(bf16x8 a, bf16x8 b, f32x4 c) {
  return __builtin_amdgcn_mfma_f32_16x16x32_bf16(a, b, c, 0, 0, 0);
}

DEV float bf2f(bf16 x) { return __bfloat162float(x); }
DEV bf16  f2bf(float x) { return __float2bfloat16(x); }

// ---------------------------------------------------------------------------
// Weight transpose+convert: f32 [K][N] -> bf16 [N][K]
// ---------------------------------------------------------------------------
struct TJob { const float* src; bf16* dst; int K; int N; };
struct TJobs { TJob j[14]; int cum[15]; };

__global__ __launch_bounds__(256) void wt_transpose(TJobs P) {
  __shared__ bf16 tile[64][65];
  int bid = blockIdx.x;
  int ji = 0;
  while (ji < 13 && bid >= P.cum[ji + 1]) ji++;
  const TJob jb = P.j[ji];
  int rel = bid - P.cum[ji];
  int ntc = jb.N >> 6;
  int tr = rel / ntc, tc = rel - tr * ntc;
  int r0 = tr << 6, c0 = tc << 6;
  int t = threadIdx.x;
  #pragma unroll
  for (int i = 0; i < 16; i++) {
    int idx = i * 256 + t;
    int r = idx >> 6, c = idx & 63;
    tile[c][r] = f2bf(jb.src[(size_t)(r0 + r) * jb.N + c0 + c]);
  }
  __syncthreads();
  #pragma unroll
  for (int i = 0; i < 16; i++) {
    int idx = i * 256 + t;
    int r = idx >> 6, c = idx & 63;
    jb.dst[(size_t)(c0 + r) * jb.K + r0 + c] = tile[r][c];
  }
}

// bf16 transpose for V: v_all [B*TT][NKVH*HDM] -> vt [B*NKVH][HDM][TT]
__global__ __launch_bounds__(256) void transpose_v(const bf16* __restrict__ v_all,
                                                   bf16* __restrict__ vt) {
  int st = blockIdx.x, ht = blockIdx.y, bk = blockIdx.z;
  int b = bk >> 3, kv = bk & 7;
  __shared__ bf16 tile[64][65];
  int t = threadIdx.x;
  int s0 = st * 64, h0 = ht * 64;
  #pragma unroll
  for (int i = 0; i < 16; i++) {
    int idx = i * 256 + t;
    int r = idx >> 6, c = idx & 63;
    tile[c][r] = v_all[((size_t)(b * TT + s0 + r) * NKVH + kv) * HDM + h0 + c];
  }
  __syncthreads();
  #pragma unroll
  for (int i = 0; i < 16; i++) {
    int idx = i * 256 + t;
    int r = idx >> 6, c = idx & 63;
    vt[((size_t)bk * HDM + h0 + r) * TT + s0 + c] = tile[r][c];
  }
}

// ---------------------------------------------------------------------------
// RMSNorm (single input)
// ---------------------------------------------------------------------------
template <int DV>
__global__ __launch_bounds__(256) void rmsnorm_k(const float* __restrict__ x,
                                                 const float* __restrict__ sc,
                                                 bf16* __restrict__ out) {
  const int D = DV * 1024;
  int row = blockIdx.x, t = threadIdx.x;
  const float4* xr = reinterpret_cast<const float4*>(x + (size_t)row * D);
  float4 v[DV];
  float ss = 0.f;
  #pragma unroll
  for (int i = 0; i < DV; i++) {
    v[i] = xr[t + i * 256];
    ss += v[i].x * v[i].x + v[i].y * v[i].y + v[i].z * v[i].z + v[i].w * v[i].w;
  }
  #pragma unroll
  for (int o = 1; o < 64; o <<= 1) ss += __shfl_xor(ss, o);
  __shared__ float red[4];
  if ((t & 63) == 0) red[t >> 6] = ss;
  __syncthreads();
  float r = rsqrtf((red[0] + red[1] + red[2] + red[3]) * (1.0f / D) + 1e-6f);
  bf16* orow = out + (size_t)row * D;
  #pragma unroll
  for (int i = 0; i < DV; i++) {
    int c = (t + i * 256) * 4;
    orow[c + 0] = f2bf(v[i].x * r * (1.f + sc[c + 0]));
    orow[c + 1] = f2bf(v[i].y * r * (1.f + sc[c + 1]));
    orow[c + 2] = f2bf(v[i].z * r * (1.f + sc[c + 2]));
    orow[c + 3] = f2bf(v[i].w * r * (1.f + sc[c + 3]));
  }
}

// ---------------------------------------------------------------------------
// RMSNorm over (p0+p1+x): fused wo split-K=2 reduce + pre-FFW norm
// ---------------------------------------------------------------------------
template <int DV>
__global__ __launch_bounds__(256) void rmsnorm2_k(
    const float* __restrict__ p0, const float* __restrict__ p1,
    const float* __restrict__ x, const float* __restrict__ sc,
    bf16* __restrict__ out) {
  const int D = DV * 1024;
  int row = blockIdx.x, t = threadIdx.x;
  size_t rb = (size_t)row * (D / 4);
  const float4* r0 = reinterpret_cast<const float4*>(p0) + rb;
  const float4* r1 = reinterpret_cast<const float4*>(p1) + rb;
  const float4* xr = reinterpret_cast<const float4*>(x) + rb;
  float4 v[DV];
  float ss = 0.f;
  #pragma unroll
  for (int i = 0; i < DV; i++) {
    int idx = t + i * 256;
    float4 a = r0[idx], b = r1[idx], e = xr[idx];
    v[i] = make_float4(a.x + b.x + e.x, a.y + b.y + e.y,
                       a.z + b.z + e.z, a.w + b.w + e.w);
    ss += v[i].x * v[i].x + v[i].y * v[i].y + v[i].z * v[i].z + v[i].w * v[i].w;
  }
  #pragma unroll
  for (int o = 1; o < 64; o <<= 1) ss += __shfl_xor(ss, o);
  __shared__ float red[4];
  if ((t & 63) == 0) red[t >> 6] = ss;
  __syncthreads();
  float r = rsqrtf((red[0] + red[1] + red[2] + red[3]) * (1.0f / D) + 1e-6f);
  bf16* orow = out + (size_t)row * D;
  #pragma unroll
  for (int i = 0; i < DV; i++) {
    int c = (t + i * 256) * 4;
    orow[c + 0] = f2bf(v[i].x * r * (1.f + sc[c + 0]));
    orow[c + 1] = f2bf(v[i].y * r * (1.f + sc[c + 1]));
    orow[c + 2] = f2bf(v[i].z * r * (1.f + sc[c + 2]));
    orow[c + 3] = f2bf(v[i].w * r * (1.f + sc[c + 3]));
  }
}

// ---------------------------------------------------------------------------
// RoPE in-place
// ---------------------------------------------------------------------------
__global__ __launch_bounds__(256) void rope_inplace(bf16* __restrict__ x, int lognh,
                                                    float scale) {
  int gid = blockIdx.x * 256 + threadIdx.x;
  int i = gid & 63;
  int rh = gid >> 6;
  int row = rh >> lognh;
  int pos = row >= TT ? row - TT : row;
  float fr = expf(-9.210340371976184f * ((float)(2 * i) * (1.0f / 128.0f)));
  float th = (float)pos * fr;
  float s, c;
  sincosf(th, &s, &c);
  bf16* p = x + (size_t)rh * HDM;
  float x1 = bf2f(p[i]), x2 = bf2f(p[i + 64]);
  p[i]      = f2bf((x1 * c - x2 * s) * scale);
  p[i + 64] = f2bf((x2 * c + x1 * s) * scale);
}

// ---------------------------------------------------------------------------
// 8-phase 256x256 GEMM - reduced-barrier K-loop (3 barriers/tile).
// ---------------------------------------------------------------------------
struct G8Job {
  const bf16* A; const bf16* B; bf16* Cb; float* Cf;
  int K, N, lda, ldb;
  int a_base, a_lsh, a_lskip;
  int c_base, c_lsh, c_lskip, c_stride;
};
struct G8Jobs { G8Job j[8]; int cum[9]; int nj; };

#define G8_MFMA(MH, NH)                                            \
  __builtin_amdgcn_s_setprio(1);                                   \
  _Pragma("unroll")                                                \
  for (int i = 0; i < 4; i++)                                      \
    _Pragma("unroll")                                              \
    for (int nj2 = 0; nj2 < 2; nj2++)                              \
      _Pragma("unroll")                                            \
      for (int kk = 0; kk < 2; kk++)                               \
        acc[(MH)*4 + i][(NH)*2 + nj2] = mfma16(                    \
            afr[i][kk], bfr[(NH)*2 + nj2][kk],                     \
            acc[(MH)*4 + i][(NH)*2 + nj2]);                        \
  __builtin_amdgcn_s_setprio(0);

__global__ __launch_bounds__(512, 2) void gemm8(G8Jobs P) {
  extern __shared__ __align__(16) bf16 lds8[];
  int bid = blockIdx.x;
  int ji = 0;
  while (ji < P.nj - 1 && bid >= P.cum[ji + 1]) ji++;
  const G8Job jb = P.j[ji];
  int rel = bid - P.cum[ji];
  int tn = jb.N >> 8;
  int bm = rel / tn, bn = rel - bm * tn;
  const int m0 = bm << 8, n0 = bn << 8;
  const int K = jb.K;
  const int nk = K >> 6;

  const int tid = threadIdx.x;
  const int w = tid >> 6, l = tid & 63;
  const int lr = l & 15, lk = l >> 4;
  const int wr = w >> 2, wc = w & 3;

  const int r0 = tid >> 3, sl0 = (tid & 7) ^ (r0 & 7);
  const int dst0 = (w * 64) * 8;
  const int dst1 = (512 + w * 64) * 8;

  auto stage = [&](int ht, int hq) {
    int k0 = ht << 6;
    bf16* ldsb = lds8 + ((ht & 1) * 32768 + hq * 8192);
    if (hq < 2) {
      int ma = m0 + hq * 128;
      int mr0 = ma + r0, mr1 = ma + 64 + r0;
      int pr0 = jb.a_base + mr0 + ((mr0 >> jb.a_lsh) * jb.a_lskip);
      int pr1 = jb.a_base + mr1 + ((mr1 >> jb.a_lsh) * jb.a_lskip);
      async_load16(jb.A + (size_t)pr0 * jb.lda + k0 + sl0 * 8, ldsb + dst0);
      async_load16(jb.A + (size_t)pr1 * jb.lda + k0 + sl0 * 8, ldsb + dst1);
    } else {
      int nb = n0 + (hq - 2) * 128;
      async_load16(jb.B + (size_t)(nb + r0) * jb.ldb + k0 + sl0 * 8, ldsb + dst0);
      async_load16(jb.B + (size_t)(nb + 64 + r0) * jb.ldb + k0 + sl0 * 8, ldsb + dst1);
    }
  };

  f32x4 acc[8][4];
  #pragma unroll
  for (int i = 0; i < 8; i++)
    #pragma unroll
    for (int j = 0; j < 4; j++) acc[i][j] = (f32x4){0.f, 0.f, 0.f, 0.f};

  const int s0 = ((0 * 4 + lk) ^ (lr & 7)) * 8;
  const int s1 = ((1 * 4 + lk) ^ (lr & 7)) * 8;
  const int browb = (wc & 1) * 64;

  #pragma unroll
  for (int hq = 0; hq < 4; hq++) stage(0, hq);
  #pragma unroll
  for (int hq = 0; hq < 4; hq++) stage(1, hq);
  asm volatile("s_waitcnt vmcnt(8)" ::: "memory");
  __builtin_amdgcn_s_barrier();
  asm volatile("" ::: "memory");

  bf16x8 afr[4][2], bfr[4][2];

  for (int t = 0; t < nk; t++) {
    const bf16* bufA = lds8 + (t & 1) * 32768 + wr * 8192;
    const bf16* bufB = lds8 + (t & 1) * 32768 + 16384 + (wc >> 1) * 8192;
    const bool st = (t + 2 < nk);

    // ---- q0: read A-low + B-low; MFMA (0,0). No barrier needed: tile t's
    //      data was globalized at t-1 q3 (vmcnt+barrier). ----
    #pragma unroll
    for (int i = 0; i < 4; i++) {
      int rb = (i * 16 + lr) * 64;
      afr[i][0] = *reinterpret_cast<const bf16x8*>(bufA + rb + s0);
      afr[i][1] = *reinterpret_cast<const bf16x8*>(bufA + rb + s1);
    }
    #pragma unroll
    for (int ni = 0; ni < 2; ni++) {
      int rb = (browb + ni * 16 + lr) * 64;
      bfr[ni][0] = *reinterpret_cast<const bf16x8*>(bufB + rb + s0);
      bfr[ni][1] = *reinterpret_cast<const bf16x8*>(bufB + rb + s1);
    }
    asm volatile("s_waitcnt lgkmcnt(0)" ::: "memory");
    __builtin_amdgcn_sched_barrier(0);
    G8_MFMA(0, 0)

    // ---- q1: read B-high; MFMA (0,1); barrier => all B reads retired ----
    #pragma unroll
    for (int ni = 2; ni < 4; ni++) {
      int rb = (browb + ni * 16 + lr) * 64;
      bfr[ni][0] = *reinterpret_cast<const bf16x8*>(bufB + rb + s0);
      bfr[ni][1] = *reinterpret_cast<const bf16x8*>(bufB + rb + s1);
    }
    asm volatile("s_waitcnt lgkmcnt(0)" ::: "memory");
    __builtin_amdgcn_sched_barrier(0);
    G8_MFMA(0, 1)
    __builtin_amdgcn_s_barrier();
    asm volatile("" ::: "memory");

    // ---- q2: read A-high; stage B-halves of t+2 (B slots retired);
    //      MFMA (1,0); barrier => all A reads retired ----
    #pragma unroll
    for (int i = 0; i < 4; i++) {
      int rb = ((i + 4) * 16 + lr) * 64;
      afr[i][0] = *reinterpret_cast<const bf16x8*>(bufA + rb + s0);
      afr[i][1] = *reinterpret_cast<const bf16x8*>(bufA + rb + s1);
    }
    if (st) { stage(t + 2, 2); stage(t + 2, 3); }
    asm volatile("s_waitcnt lgkmcnt(0)" ::: "memory");
    __builtin_amdgcn_sched_barrier(0);
    G8_MFMA(1, 0)
    __builtin_amdgcn_s_barrier();
    asm volatile("" ::: "memory");

    // ---- q3: stage A-halves of t+2 (A slots retired); counted vmcnt;
    //      MFMA (1,1); tile-boundary barrier globalizes the vmcnt ----
    if (st) {
      stage(t + 2, 0); stage(t + 2, 1);
      asm volatile("s_waitcnt vmcnt(8)" ::: "memory");  // tile t+1 resident
    } else if (t == nk - 2) {
      asm volatile("s_waitcnt vmcnt(0)" ::: "memory");
    }
    G8_MFMA(1, 1)
    __builtin_amdgcn_s_barrier();
    asm volatile("" ::: "memory");
  }

  if (jb.Cf) {
    #pragma unroll
    for (int mi = 0; mi < 8; mi++)
      #pragma unroll
      for (int jj = 0; jj < 4; jj++) {
        int m = m0 + wr * 128 + mi * 16 + lk * 4 + jj;
        float* drow = jb.Cf + (size_t)m * jb.c_stride + n0 + wc * 64;
        #pragma unroll
        for (int ni = 0; ni < 4; ni++) drow[ni * 16 + lr] = acc[mi][ni][jj];
      }
  } else {
    #pragma unroll
    for (int mi = 0; mi < 8; mi++)
      #pragma unroll
      for (int jj = 0; jj < 4; jj++) {
        int m = m0 + wr * 128 + mi * 16 + lk * 4 + jj;
        int crow = jb.c_base + m + ((m >> jb.c_lsh) * jb.c_lskip);
        bf16* drow = jb.Cb + (size_t)crow * jb.c_stride + n0 + wc * 64;
        #pragma unroll
        for (int ni = 0; ni < 4; ni++) drow[ni * 16 + lr] = f2bf(acc[mi][ni][jj]);
      }
  }
}

// ---------------------------------------------------------------------------
// Down split-K reduce: img out += p1+p2+p3+x ; txt out += q1..q7+x
// ---------------------------------------------------------------------------
__global__ __launch_bounds__(256) void reduce_down(
    float* __restrict__ oi, const float* __restrict__ a1,
    const float* __restrict__ a2, const float* __restrict__ a3,
    const float* __restrict__ xi, int n4i,
    float* __restrict__ ot, const float* __restrict__ b1,
    const float* __restrict__ b2, const float* __restrict__ b3,
    const float* __restrict__ b4, const float* __restrict__ b5,
    const float* __restrict__ b6, const float* __restrict__ b7,
    const float* __restrict__ xt, int n4t) {
  int tot = n4i + n4t;
  for (int idx = blockIdx.x * 256 + threadIdx.x; idx < tot; idx += gridDim.x * 256) {
    if (idx < n4i) {
      float4 d = ((const float4*)oi)[idx];
      float4 a = ((const float4*)a1)[idx];
      float4 b = ((const float4*)a2)[idx];
      float4 c = ((const float4*)a3)[idx];
      float4 e = ((const float4*)xi)[idx];
      ((float4*)oi)[idx] = make_float4(d.x + a.x + b.x + c.x + e.x,
                                       d.y + a.y + b.y + c.y + e.y,
                                       d.z + a.z + b.z + c.z + e.z,
                                       d.w + a.w + b.w + c.w + e.w);
    } else {
      int i = idx - n4i;
      float4 d = ((const float4*)ot)[i];
      float4 p1 = ((const float4*)b1)[i];
      float4 p2 = ((const float4*)b2)[i];
      float4 p3 = ((const float4*)b3)[i];
      float4 p4 = ((const float4*)b4)[i];
      float4 p5 = ((const float4*)b5)[i];
      float4 p6 = ((const float4*)b6)[i];
      float4 p7 = ((const float4*)b7)[i];
      float4 e = ((const float4*)xt)[i];
      ((float4*)ot)[i] = make_float4(
          d.x + p1.x + p2.x + p3.x + p4.x + p5.x + p6.x + p7.x + e.x,
          d.y + p1.y + p2.y + p3.y + p4.y + p5.y + p6.y + p7.y + e.y,
          d.z + p1.z + p2.z + p3.z + p4.z + p5.z + p6.z + p7.z + e.z,
          d.w + p1.w + p2.w + p3.w + p4.w + p5.w + p6.w + p7.w + e.w);
    }
  }
}

// ---------------------------------------------------------------------------
// In-place GELU(gate)*up over gu buffers: act written to gate half.
// ---------------------------------------------------------------------------
__global__ __launch_bounds__(256) void gelu_mul(bf16* __restrict__ gu_i,
                                                bf16* __restrict__ gu_t) {
  const int IMG_CH = 2048 * 8192 / 8;
  const int TXT_CH = 1024 * 4096 / 8;
  int idx = blockIdx.x * 256 + threadIdx.x;
  int total = IMG_CH + TXT_CH;
  if (idx >= total) return;
  bf16* base;
  int half, ci;
  if (idx < IMG_CH) { base = gu_i; half = 8192; ci = idx; }
  else              { base = gu_t; half = 4096; ci = idx - IMG_CH; }
  int rowlen = half * 2;
  int perrow = half / 8;
  int m = ci / perrow, n8 = ci - m * perrow;
  bf16* gp = base + (size_t)m * rowlen + n8 * 8;
  bf16* up = gp + half;
  bf16x8 g8 = *reinterpret_cast<const bf16x8*>(gp);
  bf16x8 u8 = *reinterpret_cast<const bf16x8*>(up);
  bf16x8 o8;
  #pragma unroll
  for (int i = 0; i < 8; i++) {
    float g = (float)g8[i], u = (float)u8[i];
    float t = tanhf(0.7978845608028654f * (g + 0.044715f * g * g * g));
    o8[i] = (__bf16)(0.5f * g * (1.f + t) * u);
  }
  *reinterpret_cast<bf16x8*>(gp) = o8;
}

// ---------------------------------------------------------------------------
// Flash attention with softcap (no online max; logits bounded by +-50).
// ---------------------------------------------------------------------------
__global__ __launch_bounds__(256) void attn_k(const bf16* __restrict__ q_all,
                                              const bf16* __restrict__ k_all,
                                              const bf16* __restrict__ vt,
                                              bf16* __restrict__ attn_o) {
  const int qt = blockIdx.x;
  const int n = blockIdx.y;
  const int b = blockIdx.z;
  const int kv = n >> 1;
  const int tid = threadIdx.x, w = tid >> 6, l = tid & 63;
  const int lr = l & 15, lk = l >> 4;
  __shared__ __align__(16) bf16 Ksm[64 * 128];
  __shared__ __align__(16) bf16 Vsm[128 * 64];
  __shared__ __align__(16) bf16 Psm[4][16][72];

  bf16x8 qf[4];
  {
    int t = qt * 64 + w * 16 + lr;
    const bf16* qp = q_all + ((size_t)(b * TT + t) * NHQ + n) * HDM;
    #pragma unroll
    for (int kk = 0; kk < 4; kk++)
      qf[kk] = *reinterpret_cast<const bf16x8*>(qp + kk * 32 + lk * 8);
  }
  f32x4 acc_o[8];
  #pragma unroll
  for (int i = 0; i < 8; i++) acc_o[i] = (f32x4){0.f, 0.f, 0.f, 0.f};
  float den[4] = {0.f, 0.f, 0.f, 0.f};

  for (int st = 0; st < TT / 64; st++) {
    __syncthreads();
    #pragma unroll
    for (int i = 0; i < 4; i++) {
      int cb = (w * 4 + i) * 64;
      int c = cb + l;
      {
        int srow = c >> 4, c16 = c & 15;
        const bf16* g = k_all + ((size_t)(b * TT + st * 64 + srow) * NKVH + kv) * HDM +
                        ((c16 ^ (srow & 7)) << 3);
        async_load16(g, Ksm + cb * 8);
      }
      {
        int hrow = c >> 3, c8 = c & 7;
        const bf16* g = vt + ((size_t)(b * NKVH + kv) * HDM + hrow) * TT + st * 64 +
                        ((c8 ^ (hrow & 7)) << 3);
        async_load16(g, Vsm + cb * 8);
      }
    }
    __syncthreads();
    #pragma unroll
    for (int sf = 0; sf < 4; sf++) {
      f32x4 s4 = (f32x4){0.f, 0.f, 0.f, 0.f};
      int sl = sf * 16 + lr;
      #pragma unroll
      for (int kk = 0; kk < 4; kk++) {
        int e = kk * 32 + lk * 8;
        bf16x8 kf = *reinterpret_cast<const bf16x8*>(
            Ksm + sl * 128 + ((((e >> 3) ^ (sl & 7))) << 3));
        s4 = mfma16(qf[kk], kf, s4);
      }
      #pragma unroll
      for (int j = 0; j < 4; j++) {
        float xv = s4[j];
        float tcap = tanhf(xv * 0.02f) * 50.f;
        float p = __expf(tcap);
        Psm[w][lk * 4 + j][sf * 16 + lr] = f2bf(p);
        p += __shfl_xor(p, 1);
        p += __shfl_xor(p, 2);
        p += __shfl_xor(p, 4);
        p += __shfl_xor(p, 8);
        den[j] += p;
      }
    }
    #pragma unroll
    for (int kk2 = 0; kk2 < 2; kk2++) {
      bf16x8 pa = *reinterpret_cast<const bf16x8*>(&Psm[w][lr][kk2 * 32 + lk * 8]);
      #pragma unroll
      for (int hf = 0; hf < 8; hf++) {
        int h = hf * 16 + lr;
        int e2 = kk2 * 32 + lk * 8;
        bf16x8 vb = *reinterpret_cast<const bf16x8*>(
            Vsm + h * 64 + ((((e2 >> 3) ^ (h & 7))) << 3));
        acc_o[hf] = mfma16(pa, vb, acc_o[hf]);
      }
    }
  }
  #pragma unroll
  for (int hf = 0; hf < 8; hf++)
    #pragma unroll
    for (int j = 0; j < 4; j++) {
      int t = qt * 64 + w * 16 + lk * 4 + j;
      float val = acc_o[hf][j] / den[j];
      attn_o[((size_t)(b * TT + t)) * (NHQ * HDM) + n * HDM + hf * 16 + lr] = f2bf(val);
    }
}

// ---------------------------------------------------------------------------
extern "C" void kernel_launch(void* const* d_in, const int* in_sizes, int n_in,
                              void* d_out, int out_size, void* d_ws,
                              size_t ws_size, hipStream_t stream) {
  const float* x_img = (const float*)d_in[0];
  const float* x_txt = (const float*)d_in[1];
  const float* sc_attn_i = (const float*)d_in[3];
  const float* wq_i = (const float*)d_in[4];
  const float* wk_i = (const float*)d_in[5];
  const float* wv_i = (const float*)d_in[6];
  const float* wo_i = (const float*)d_in[7];
  const float* sc_ffw_i = (const float*)d_in[8];
  const float* wg_i = (const float*)d_in[9];
  const float* wu_i = (const float*)d_in[10];
  const float* wd_i = (const float*)d_in[11];
  const float* sc_attn_t = (const float*)d_in[12];
  const float* wq_t = (const float*)d_in[13];
  const float* wk_t = (const float*)d_in[14];
  const float* wv_t = (const float*)d_in[15];
  const float* wo_t = (const float*)d_in[16];
  const float* sc_ffw_t = (const float*)d_in[17];
  const float* wg_t = (const float*)d_in[18];
  const float* wu_t = (const float*)d_in[19];
  const float* wd_t = (const float*)d_in[20];
  float* outp = (float*)d_out;
  float* outp_t = outp + (size_t)2 * 1024 * 2048;

  char* ws = (char*)d_ws;
  size_t off = 0;
  auto alloc = [&](size_t n) {
    char* p = ws + off;
    off += (n + 255) & ~(size_t)255;
    return p;
  };
  bf16* WqT_i = (bf16*)alloc((size_t)2048 * 2048 * 2);
  bf16* WkT_i = (bf16*)alloc((size_t)1024 * 2048 * 2);
  bf16* WvT_i = (bf16*)alloc((size_t)1024 * 2048 * 2);
  bf16* WoT_i = (bf16*)alloc((size_t)2048 * 2048 * 2);
  bf16* WguT_i = (bf16*)alloc((size_t)16384 * 2048 * 2);  // 64 MB
  bf16* WdT_i = (bf16*)alloc((size_t)2048 * 8192 * 2);
  bf16* WqT_t = (bf16*)alloc((size_t)2048 * 1024 * 2);
  bf16* WkT_t = (bf16*)alloc((size_t)1024 * 1024 * 2);
  bf16* WvT_t = (bf16*)alloc((size_t)1024 * 1024 * 2);
  bf16* WoT_t = (bf16*)alloc((size_t)1024 * 2048 * 2);
  bf16* WguT_t = (bf16*)alloc((size_t)8192 * 1024 * 2);   // 16 MB
  bf16* WdT_t = (bf16*)alloc((size_t)1024 * 4096 * 2);
  bf16* xn_i = (bf16*)alloc((size_t)2048 * 2048 * 2);
  bf16* xn_t = (bf16*)alloc((size_t)1024 * 1024 * 2);
  float* h_i = (float*)alloc((size_t)2048 * 2048 * 4);  // wo p0 img
  float* h_t = (float*)alloc((size_t)1024 * 1024 * 4);  // wo p0 txt
  char* S = (char*)alloc((size_t)84 * 1024 * 1024);
  (void)ws_size;

  const size_t MB = 1024 * 1024;
  // phase A (attention)
  bf16* q_all = (bf16*)S;
  bf16* k_all = (bf16*)(S + 12 * MB);
  bf16* v_all = (bf16*)(S + 18 * MB);
  bf16* vtr   = (bf16*)(S + 24 * MB);
  bf16* attn_o= (bf16*)(S + 30 * MB);      // live through wo
  // wo split-K=2 p1 partials over dead q/k region
  float* wp1_i = (float*)S;                // 16 MB
  float* wp1_t = (float*)(S + 16 * MB);    // 4 MB
  // phase FFN
  bf16* gu_i  = (bf16*)S;                  // 64 MB
  bf16* gu_t  = (bf16*)(S + 64 * MB);      // 16 MB
  // down partials over dead WguT regions (re-transposed every call)
  float* dp1 = (float*)WguT_i;                       // img 16 MB
  float* dp2 = (float*)((char*)WguT_i + 16 * MB);    // img 16 MB
  float* dp3 = (float*)((char*)WguT_i + 32 * MB);    // img 16 MB
  float* dt1 = (float*)((char*)WguT_i + 48 * MB);    // txt 4 MB
  float* dt2 = (float*)((char*)WguT_i + 52 * MB);
  float* dt3 = (float*)((char*)WguT_i + 56 * MB);
  float* dt4 = (float*)((char*)WguT_i + 60 * MB);
  float* dt5 = (float*)WguT_t;
  float* dt6 = (float*)((char*)WguT_t + 4 * MB);
  float* dt7 = (float*)((char*)WguT_t + 8 * MB);

  (void)hipFuncSetAttribute(reinterpret_cast<const void*>(gemm8),
                            hipFuncAttributeMaxDynamicSharedMemorySize, 131072);

  // 1. weight transpose/convert
  TJobs tj;
  auto setj = [&](int idx, const float* s, bf16* d, int K, int N) {
    tj.j[idx].src = s; tj.j[idx].dst = d; tj.j[idx].K = K; tj.j[idx].N = N;
  };
  setj(0, wq_i, WqT_i, 2048, 2048);
  setj(1, wk_i, WkT_i, 2048, 1024);
  setj(2, wv_i, WvT_i, 2048, 1024);
  setj(3, wo_i, WoT_i, 2048, 2048);
  setj(4, wg_i, WguT_i, 2048, 8192);
  setj(5, wu_i, WguT_i + (size_t)8192 * 2048, 2048, 8192);
  setj(6, wd_i, WdT_i, 8192, 2048);
  setj(7, wq_t, WqT_t, 1024, 2048);
  setj(8, wk_t, WkT_t, 1024, 1024);
  setj(9, wv_t, WvT_t, 1024, 1024);
  setj(10, wo_t, WoT_t, 2048, 1024);
  setj(11, wg_t, WguT_t, 1024, 4096);
  setj(12, wu_t, WguT_t + (size_t)4096 * 1024, 1024, 4096);
  setj(13, wd_t, WdT_t, 4096, 1024);
  tj.cum[0] = 0;
  for (int i = 0; i < 14; i++)
    tj.cum[i + 1] = tj.cum[i] + (tj.j[i].K >> 6) * (tj.j[i].N >> 6);
  wt_transpose<<<tj.cum[14], 256, 0, stream>>>(tj);

  // 2. pre-attn RMSNorm
  rmsnorm_k<2><<<2048, 256, 0, stream>>>(x_img, sc_attn_i, xn_i);
  rmsnorm_k<1><<<1024, 256, 0, stream>>>(x_txt, sc_attn_t, xn_t);

  auto mk8b = [](const bf16* A, const bf16* B, bf16* Cb, int K, int N, int lda,
                 int ldb, int ab, int ash, int ask, int cb2, int csh, int csk,
                 int cstr) {
    G8Job g{};
    g.A = A; g.B = B; g.Cb = Cb; g.Cf = nullptr;
    g.K = K; g.N = N; g.lda = lda; g.ldb = ldb;
    g.a_base = ab; g.a_lsh = ash; g.a_lskip = ask;
    g.c_base = cb2; g.c_lsh = csh; g.c_lskip = csk; g.c_stride = cstr;
    return g;
  };
  auto mk8f = [](const bf16* A, const bf16* B, float* Cf, int K, int N, int lda,
                 int ldb, int ab, int ash, int ask, int cstr) {
    G8Job g{};
    g.A = A; g.B = B; g.Cb = nullptr; g.Cf = Cf;
    g.K = K; g.N = N; g.lda = lda; g.ldb = ldb;
    g.a_base = ab; g.a_lsh = ash; g.a_lskip = ask;
    g.c_base = 0; g.c_lsh = 30; g.c_lskip = 0; g.c_stride = cstr;
    return g;
  };
  auto launch8 = [&](G8Jobs& P, int nj, const int* Mt) {
    P.nj = nj;
    P.cum[0] = 0;
    for (int i = 0; i < nj; i++) P.cum[i + 1] = P.cum[i] + Mt[i] * (P.j[i].N >> 8);
    gemm8<<<P.cum[nj], 512, 131072, stream>>>(P);
  };

  // 3. QKV via gemm8
  {
    G8Jobs P;
    P.j[0] = mk8b(xn_i, WqT_i, q_all, 2048, 2048, 2048, 2048, 0, 30, 0, 0, 10, 512, 2048);
    P.j[1] = mk8b(xn_i, WkT_i, k_all, 2048, 1024, 2048, 2048, 0, 30, 0, 0, 10, 512, 1024);
    P.j[2] = mk8b(xn_i, WvT_i, v_all, 2048, 1024, 2048, 2048, 0, 30, 0, 0, 10, 512, 1024);
    P.j[3] = mk8b(xn_t, WqT_t, q_all, 1024, 2048, 1024, 1024, 0, 30, 0, 1024, 9, 1024, 2048);
    P.j[4] = mk8b(xn_t, WkT_t, k_all, 1024, 1024, 1024, 1024, 0, 30, 0, 1024, 9, 1024, 1024);
    P.j[5] = mk8b(xn_t, WvT_t, v_all, 1024, 1024, 1024, 1024, 0, 30, 0, 1024, 9, 1024, 1024);
    int Mt[6] = {8, 8, 8, 4, 4, 4};
    launch8(P, 6, Mt);
  }

  // 4. RoPE
  rope_inplace<<<12288, 256, 0, stream>>>(q_all, 4, 0.08838834764831845f);
  rope_inplace<<<6144, 256, 0, stream>>>(k_all, 3, 1.0f);

  // 5. V transpose
  transpose_v<<<dim3(24, 2, 16), 256, 0, stream>>>(v_all, vtr);

  // 6. attention
  attn_k<<<dim3(24, 16, 2), 256, 0, stream>>>(q_all, k_all, vtr, attn_o);

  // 7. WO split-K=2 (160 blocks): p0 -> h, p1 -> wp1
  {
    G8Jobs P;
    P.j[0] = mk8f(attn_o,        WoT_i,        h_i,   1024, 2048, 2048, 2048, 0, 10, 512, 2048);
    P.j[1] = mk8f(attn_o + 1024, WoT_i + 1024, wp1_i, 1024, 2048, 2048, 2048, 0, 10, 512, 2048);
    P.j[2] = mk8f(attn_o,        WoT_t,        h_t,   1024, 1024, 2048, 2048, 1024, 9, 1024, 1024);
    P.j[3] = mk8f(attn_o + 1024, WoT_t + 1024, wp1_t, 1024, 1024, 2048, 2048, 1024, 9, 1024, 1024);
    int Mt[4] = {8, 8, 4, 4};
    launch8(P, 4, Mt);
  }

  // 8. fused (p0+p1+x) RMSNorm -> xn
  rmsnorm2_k<2><<<2048, 256, 0, stream>>>(h_i, wp1_i, x_img, sc_ffw_i, xn_i);
  rmsnorm2_k<1><<<1024, 256, 0, stream>>>(h_t, wp1_t, x_txt, sc_ffw_t, xn_t);

  // 9. gate|up via gemm8 -> gu (bf16), single launch (640 blocks)
  {
    G8Jobs P;
    P.j[0] = mk8b(xn_i, WguT_i, gu_i, 2048, 16384, 2048, 2048, 0, 30, 0, 0, 30, 0, 16384);
    P.j[1] = mk8b(xn_t, WguT_t, gu_t, 1024, 8192, 1024, 1024, 0, 30, 0, 0, 30, 0, 8192);
    int Mt[2] = {8, 4};
    launch8(P, 2, Mt);
  }
  {
    int total = 2048 * 8192 / 8 + 1024 * 4096 / 8;
    gelu_mul<<<(total + 255) / 256, 256, 0, stream>>>(gu_i, gu_t);
  }

  // 10a. DOWN img split-4 (256 blocks nk=32, 1 clean round); p0 -> d_out
  {
    G8Jobs P;
    P.j[0] = mk8f(gu_i,        WdT_i,        outp, 2048, 2048, 16384, 8192, 0, 30, 0, 2048);
    P.j[1] = mk8f(gu_i + 2048, WdT_i + 2048, dp1,  2048, 2048, 16384, 8192, 0, 30, 0, 2048);
    P.j[2] = mk8f(gu_i + 4096, WdT_i + 4096, dp2,  2048, 2048, 16384, 8192, 0, 30, 0, 2048);
    P.j[3] = mk8f(gu_i + 6144, WdT_i + 6144, dp3,  2048, 2048, 16384, 8192, 0, 30, 0, 2048);
    int Mt[4] = {8, 8, 8, 8};
    launch8(P, 4, Mt);
  }
  // 10b. DOWN txt split-8 (128 blocks nk=8, short round 2); p0 -> d_out
  {
    G8Jobs P;
    float* dst[8] = {outp_t, dt1, dt2, dt3, dt4, dt5, dt6, dt7};
    for (int s = 0; s < 8; s++)
      P.j[s] = mk8f(gu_t + s * 512, WdT_t + s * 512, dst[s], 512, 1024, 8192,
                    4096, 0, 30, 0, 1024);
    int Mt[8] = {4, 4, 4, 4, 4, 4, 4, 4};
    launch8(P, 8, Mt);
  }
  reduce_down<<<2048, 256, 0, stream>>>(
      outp, dp1, dp2, dp3, x_img, 2048 * 2048 / 4,
      outp_t, dt1, dt2, dt3, dt4, dt5, dt6, dt7, x_txt, 1024 * 1024 / 4);
}